// Round 7
// baseline (603.721 us; speedup 1.0000x reference)
//
#include <hip/hip_runtime.h>

typedef _Float16 half8  __attribute__((ext_vector_type(8)));
typedef _Float16 half4v __attribute__((ext_vector_type(4)));
typedef float  floatx4  __attribute__((ext_vector_type(4)));

#define MFMA16(A,B,C) __builtin_amdgcn_mfma_f32_16x16x32_f16((A),(B),(C),0,0,0)

#define L2E  1.4426950408889634f
#define L2E2 2.8853900817779268f

// prescaled-domain activations: y = L2E*x (sig) / 2*L2E*x (tanh). One exp2 +
// one rcp each (no fast-math in harness: plain / = full IEEE divide sequence).
__device__ __forceinline__ float sig_pre(float y){
  return __builtin_amdgcn_rcpf(1.0f + __builtin_amdgcn_exp2f(-y));
}
__device__ __forceinline__ float tanh_pre(float y){
  return 1.0f - 2.0f*__builtin_amdgcn_rcpf(1.0f + __builtin_amdgcn_exp2f(y));
}
__device__ __forceinline__ float tanh_raw(float c){
  return 1.0f - 2.0f*__builtin_amdgcn_rcpf(1.0f + __builtin_amdgcn_exp2f(L2E2*c));
}
// 8B-aligned f16x8 load (2x b64) — for LDS strides that are 8B- but not 16B-multiples
__device__ __forceinline__ half8 ld8(const _Float16* p){
  half4v a = *(const half4v*)p;
  half4v b = *(const half4v*)(p+4);
  return __builtin_shufflevector(a,b,0,1,2,3,4,5,6,7);
}

// grid geometry tables (compile-time foldable)
static __device__ constexpr int DY[27] = {0,0,0,0,0,0,0,0, 1,1,1,1,1,1,1,1, 2,2, 3,3,3,4,4,4,5,5,5};
static __device__ constexpr int DX[27] = {0,1,2,3,4,5,6,7, 0,1,2,3,4,5,6,7, 0,1, 3,4,5,3,4,5,3,4,5};
static __device__ constexpr int PY[9]  = {0,0,0,0,0,0,0,1,4};
static __device__ constexpr int PX[9]  = {1,2,3,4,5,6,7,0,4};
static __device__ constexpr int OY[46] = {0,0,0,0,0,0,0,0, 1,1,1,1,1,1,1,1, 2,2,2,2,2,2,2,2,
                                          3,3,3,3,3,3,3, 4,4,4,4,4, 5,5,5,5,5, 6,6,6,6,6};
static __device__ constexpr int OX[46] = {0,1,2,3,4,5,6,7, 0,1,2,3,4,5,6,7, 0,1,2,3,4,5,6,7,
                                          0,1,2,3,4,5,6, 2,3,4,5,6, 2,3,4,5,6, 2,3,4,5,6};
__device__ constexpr int d1idx(int iy,int ix){
  return (iy<0||iy>7||ix<0||ix>7) ? -1 :
         (iy<=1) ? iy*8+ix :
         (iy==2 && ix<=1) ? 16+ix :
         (iy>=3 && iy<=5 && ix>=3 && ix<=5) ? 18+(iy-3)*3+(ix-3) : -1;
}

// ---------------------------------------------------------------------------
// Combined encoder: blocks [0,512) = target LSTM, [512,4608) = neighbor LSTM.
// One block = 16 sequences (M=16), 8 waves; wave owns 16 hidden cols x 4 gates.
// Merged-K: h row = [h(128) | x(t)(7) | 1.0 | zeros(32)], K=160 in 5 chunks.
// REGISTER DIET (vs R5, which spilled ~340 MB scratch at the 128-reg cap):
//  - A-fragments streamed one at a time (not a[5] array)
//  - kc=4 B-chunk (w_ih|bias, mostly zeros) lives in LDS (wihb), re-read per
//    step; q!=0 lanes read a shared zero row (same-address broadcast, free).
// Resident ≈ bfrag 64 + acc 16 + transients ~28 < 128 → 4 waves/SIMD, no spill.
// ---------------------------------------------------------------------------
__global__ __launch_bounds__(512, 4) void lstm_all(
    const float* __restrict__ target, const float* __restrict__ neigh,
    const float* __restrict__ e_wih, const float* __restrict__ e_whh,
    const float* __restrict__ e_bih, const float* __restrict__ e_bhh,
    const float* __restrict__ n_wih, const float* __restrict__ n_whh,
    const float* __restrict__ n_bih, const float* __restrict__ n_bhh,
    _Float16* __restrict__ h_enc16, _Float16* __restrict__ h_nb16)
{
  __shared__ _Float16 h_lds[2][16][168];   // row: 128 h + 8 x-tail + 32 zero
  __shared__ _Float16 xf16[16][168];       // [seq][t*8+f]; f==7 slot = 1.0 bias carrier
  __shared__ __align__(16) _Float16 wihb[8][4][17][8]; // [wave][gate][cb | row16=zeros][8]

  const int tid  = threadIdx.x;
  const int wv   = tid >> 6;
  const int lane = tid & 63;
  const int q    = lane >> 4;
  const int cb   = lane & 15;

  const bool enc = (blockIdx.x < 512);
  const float* x   = enc ? target : neigh;
  const float* wih = enc ? e_wih : n_wih;
  const float* whh = enc ? e_whh : n_whh;
  const float* bih = enc ? e_bih : n_bih;
  const float* bhh = enc ? e_bhh : n_bhh;
  _Float16* hout   = enc ? h_enc16 : h_nb16;
  const long base  = enc ? (long)blockIdx.x*16 : (long)(blockIdx.x-512)*16;

  for (int i = tid; i < 16*168; i += 512){
    int seq = i/168, rem = i%168, t = rem>>3, f = rem&7;
    float v = 0.f;
    if (t < 20) v = (f < 7) ? x[base*140 + seq*140 + t*7 + f] : 1.0f;
    xf16[seq][rem] = (_Float16)v;
  }
  for (int i = tid; i < 2*16*168; i += 512) ((_Float16*)h_lds)[i] = (_Float16)0.f;

  // per-wave w_ih|bias chunk into LDS (prescaled); row 16 = zeros
  if (q == 0){
    #pragma unroll
    for (int g=0; g<4; ++g){
      const float sc = (g==2) ? L2E2 : L2E;
      const int col = g*128 + wv*16 + cb;
      _Float16* d = &wihb[wv][g][cb][0];
      #pragma unroll
      for (int j=0;j<7;++j) d[j] = (_Float16)(wih[col*7+j]*sc);
      d[7] = (_Float16)((bih[col]+bhh[col])*sc);
    }
  } else if (lane == 16){
    #pragma unroll
    for (int g=0; g<4; ++g){
      _Float16* d = &wihb[wv][g][16][0];
      #pragma unroll
      for (int j=0;j<8;++j) d[j] = (_Float16)0.f;
    }
  }

  // w_hh B-frags in regs (prescaled): 4 gates x 4 chunks x 4 VGPR = 64 regs
  half8 bfrag[4][4];
  #pragma unroll
  for (int g=0; g<4; ++g){
    const float sc = (g==2) ? L2E2 : L2E;
    const int col = g*128 + wv*16 + cb;
    #pragma unroll
    for (int kc=0; kc<4; ++kc){
      const float* src = whh + (long)col*128 + kc*32 + q*8;
      half8 f;
      #pragma unroll
      for (int j=0;j<8;++j) f[j] = (_Float16)(src[j]*sc);
      bfrag[g][kc] = f;
    }
  }
  __syncthreads();
  if (tid < 16)   // x(0) + bias carrier into h(0) tail
    *(half8*)&h_lds[0][tid][128] = *(const half8*)&xf16[tid][0];
  __syncthreads();

  const int hcol = wv*16 + cb;
  const _Float16* bxp = &wihb[wv][0][(q==0)?cb:16][0];  // gate stride = 136 f16
  float c_reg[4] = {0,0,0,0};
  float h_new[4] = {0,0,0,0};
  const floatx4 ZERO4 = {0.f,0.f,0.f,0.f};

  for (int t=0; t<20; ++t){
    const _Float16* hrow = &h_lds[t&1][cb][0];
    _Float16 (*hw)[168]  = h_lds[(t+1)&1];

    floatx4 acc[4];
    {
      half8 a4 = *(const half8*)(hrow + 128 + q*8);
      #pragma unroll
      for (int g=0; g<4; ++g){
        half8 bx = *(const half8*)(bxp + g*136);
        acc[g] = MFMA16(a4, bx, ZERO4);
      }
    }
    #pragma unroll
    for (int kc=0; kc<4; ++kc){
      half8 a = *(const half8*)(hrow + kc*32 + q*8);
      #pragma unroll
      for (int g=0; g<4; ++g)
        acc[g] = MFMA16(a, bfrag[g][kc], acc[g]);
    }
    #pragma unroll
    for (int r=0; r<4; ++r){
      float ig = sig_pre(acc[0][r]);
      float fg = sig_pre(acc[1][r]);
      float gg = tanh_pre(acc[2][r]);
      float og = sig_pre(acc[3][r]);
      float c  = fg*c_reg[r] + ig*gg;
      c_reg[r] = c;
      h_new[r] = og*tanh_raw(c);
    }
    #pragma unroll
    for (int r=0; r<4; ++r) hw[q*4 + r][hcol] = (_Float16)h_new[r];
    if (tid < 16)   // x(t+1) tail into the buffer read next step
      *(half8*)&hw[tid][128] = *(const half8*)&xf16[tid][(t+1)*8];
    __syncthreads();
  }

  #pragma unroll
  for (int r=0; r<4; ++r)
    hout[(base + q*4 + r)*128 + hcol] = (_Float16)h_new[r];
}

// ---------------------------------------------------------------------------
// Prep: weights into MFMA B-fragment-friendly f16 layouts + conv2 background.
// ---------------------------------------------------------------------------
__global__ void prep_kernel(const float* __restrict__ w1, const float* __restrict__ b1,
                            const float* __restrict__ w2, const float* __restrict__ b2,
                            const float* __restrict__ fus_w,
                            _Float16* __restrict__ w1f, _Float16* __restrict__ w2f,
                            _Float16* __restrict__ fus_wf,
                            float* __restrict__ v2bg, float* __restrict__ bgmax)
{
  const int tid = threadIdx.x;
  const int gid = blockIdx.x*256 + tid;
  const int gstride = gridDim.x*256;
  for (int i = gid; i < 9*64*128; i += gstride){
    int s = i>>13, rem = i&8191, c1 = rem>>7, ci = rem&127;
    w1f[s*8448 + c1*132 + ci] = (_Float16)w1[c1*1152 + ci*9 + s];
  }
  for (int i = gid; i < 9*32*64; i += gstride){
    int s = i>>11, rem = i&2047, c2 = rem>>6, ci = rem&63;
    w2f[s*2176 + c2*68 + ci] = (_Float16)w2[c2*576 + ci*9 + s];
  }
  for (int i = gid; i < 128*160; i += gstride){
    int n = i/160, k = i%160;
    fus_wf[n*164 + k] = (_Float16)fus_w[i];
  }
  if (blockIdx.x == 0){
    __shared__ float S[288];
    __shared__ int bgm[32];
    for (int i=tid;i<288;i+=256){
      int c2=i/9, s=i%9;
      float a=0.f;
      for (int ci=0;ci<64;++ci) a += w2[c2*576+ci*9+s]*fmaxf(b1[ci],0.f);
      S[i]=a;
    }
    if (tid<32) bgm[tid]=0;
    __syncthreads();
    for (int i=tid;i<2048;i+=256){
      int cell=i>>5, c2=i&31, y=cell>>3, xx=cell&7;
      float a=b2[c2];
      for (int dy=0;dy<3;++dy){ int iy=y+dy-1; if((unsigned)iy>7u) continue;
        for (int dx=0;dx<3;++dx){ int ix=xx+dx-1; if((unsigned)ix>7u) continue;
          a += S[c2*9+dy*3+dx]; } }
      v2bg[cell*32+c2]=a;
      bool aff = (y<=2) || (y==3 && xx<=6) || (y>=4 && y<=6 && xx>=2 && xx<=6);
      if(!aff) atomicMax(&bgm[c2], __float_as_int(fmaxf(a,0.f)));
    }
    __syncthreads();
    if (tid<32) bgmax[tid]=__int_as_float(bgm[tid]);
  }
}

// ---------------------------------------------------------------------------
// Social pooling + sparse conv stack + maxpool + fusion, MFMA formulation.
// ---------------------------------------------------------------------------
__global__ __launch_bounds__(256, 1) void social_fuse(
    const _Float16* __restrict__ h_enc, const _Float16* __restrict__ h_nb,
    const _Float16* __restrict__ w1f, const _Float16* __restrict__ w2f,
    const _Float16* __restrict__ fus_wf,
    const float* __restrict__ b1, const float* __restrict__ v2bg,
    const float* __restrict__ bgmax, const float* __restrict__ fus_b,
    float* __restrict__ fused)
{
  __shared__ __align__(16) _Float16 vecs[9*16*132];
  __shared__ __align__(16) _Float16 d1[27*16*68];
  __shared__ __align__(16) _Float16 A16[16*164];
  __shared__ int pooled[512];

  const int tid  = threadIdx.x;
  const int wv   = tid >> 6;
  const int lane = tid & 63;
  const int q    = lane >> 4;
  const int cb   = lane & 15;
  const long base = (long)blockIdx.x * 16;

  for (int i=tid; i<9*16*32; i+=256){
    int p = i>>9, rem = i&511, bb = rem>>5, j = rem&31;
    const _Float16* src = (p<8) ? (h_nb + (((base+bb))*8 + p)*128 + j*4)
                                : (h_enc + (base+bb)*128 + j*4);
    *(unsigned long long*)(vecs + p*2112 + bb*132 + j*4) = *(const unsigned long long*)src;
  }
  for (int i=tid; i<512; i+=256){
    int bb=i>>5, j=i&31;
    *(unsigned long long*)(A16 + bb*164 + j*4) =
        *(const unsigned long long*)(h_enc + (base+bb)*128 + j*4);
  }
  for (int i=tid; i<512; i+=256) pooled[i] = __float_as_int(bgmax[i&31]);
  __syncthreads();

  {
    const int c1lane = wv*16 + cb;
    half8 bf1[9][4];
    #pragma unroll
    for (int s=0;s<9;++s)
      #pragma unroll
      for (int kc=0;kc<4;++kc)
        bf1[s][kc] = ld8(w1f + s*8448 + c1lane*132 + kc*32 + q*8);
    const float b1v = b1[c1lane];
    const float bg  = fmaxf(b1v, 0.f);

    #pragma unroll
    for (int ci=0; ci<27; ++ci){
      const int y = DY[ci], x = DX[ci];
      floatx4 C = {0.f,0.f,0.f,0.f};
      #pragma unroll
      for (int p=0;p<9;++p){
        const int dy = PY[p]-y+1, dx = PX[p]-x+1;
        if (dy>=0 && dy<3 && dx>=0 && dx<3){
          const int s = dy*3+dx;
          const _Float16* ap = vecs + p*2112 + cb*132 + q*8;
          #pragma unroll
          for (int kc=0;kc<4;++kc)
            C = MFMA16(ld8(ap + kc*32), bf1[s][kc], C);
        }
      }
      _Float16* dp = d1 + ci*1088 + c1lane;
      #pragma unroll
      for (int r=0;r<4;++r)
        dp[(q*4+r)*68] = (_Float16)(fmaxf(b1v + C[r], 0.f) - bg);
    }
  }
  __syncthreads();

  {
    half8 bf2[9][2][2];
    #pragma unroll
    for (int s=0;s<9;++s)
      #pragma unroll
      for (int nt=0;nt<2;++nt)
        #pragma unroll
        for (int kc=0;kc<2;++kc)
          bf2[s][nt][kc] = ld8(w2f + s*2176 + (nt*16+cb)*68 + kc*32 + q*8);

    float rm0[4] = {0,0,0,0}, rm1[4] = {0,0,0,0};
    #pragma unroll
    for (int oc=0; oc<46; ++oc){
      if ((oc & 3) != wv) continue;
      const int y = OY[oc], x = OX[oc];
      const int cell = y*8+x;
      float v0 = v2bg[cell*32 + cb];
      float v1 = v2bg[cell*32 + 16 + cb];
      floatx4 C0 = {v0,v0,v0,v0}, C1 = {v1,v1,v1,v1};
      #pragma unroll
      for (int dy=0;dy<3;++dy)
        #pragma unroll
        for (int dx=0;dx<3;++dx){
          const int dc = d1idx(y+dy-1, x+dx-1);
          if (dc < 0) continue;
          const int s = dy*3+dx;
          const _Float16* ap = d1 + dc*1088 + cb*68 + q*8;
          #pragma unroll
          for (int kc=0;kc<2;++kc){
            half8 a = ld8(ap + kc*32);
            C0 = MFMA16(a, bf2[s][0][kc], C0);
            C1 = MFMA16(a, bf2[s][1][kc], C1);
          }
        }
      #pragma unroll
      for (int r=0;r<4;++r){
        rm0[r] = fmaxf(rm0[r], fmaxf(C0[r],0.f));
        rm1[r] = fmaxf(rm1[r], fmaxf(C1[r],0.f));
      }
    }
    #pragma unroll
    for (int r=0;r<4;++r){
      atomicMax(&pooled[(q*4+r)*32 + cb],      __float_as_int(rm0[r]));
      atomicMax(&pooled[(q*4+r)*32 + 16 + cb], __float_as_int(rm1[r]));
    }
  }
  __syncthreads();

  for (int i=tid;i<512;i+=256){
    int bb=i>>5, c2=i&31;
    A16[bb*164 + 128 + c2] = (_Float16)__int_as_float(pooled[i]);
  }
  __syncthreads();

  {
    half8 bfF[2][5];
    #pragma unroll
    for (int nt2=0;nt2<2;++nt2)
      #pragma unroll
      for (int kc=0;kc<5;++kc)
        bfF[nt2][kc] = ld8(fus_wf + ((wv*2+nt2)*16+cb)*164 + kc*32 + q*8);
    const float fb0 = fus_b[(wv*2)*16+cb];
    const float fb1 = fus_b[(wv*2+1)*16+cb];
    floatx4 C0 = {0.f,0.f,0.f,0.f}, C1 = {0.f,0.f,0.f,0.f};
    #pragma unroll
    for (int kc=0;kc<5;++kc){
      half8 a = ld8(A16 + cb*164 + kc*32 + q*8);
      C0 = MFMA16(a, bfF[0][kc], C0);
      C1 = MFMA16(a, bfF[1][kc], C1);
    }
    #pragma unroll
    for (int r=0;r<4;++r){
      const long row = base + q*4 + r;
      fused[row*128 + (wv*2)*16+cb]   = tanh_raw(C0[r]+fb0);
      fused[row*128 + (wv*2+1)*16+cb] = tanh_raw(C1[r]+fb1);
    }
  }
}

// ---------------------------------------------------------------------------
// Decoder: 25 autoregressive steps. 16 seqs/block (M=16), 8 waves, 512 blocks.
// Gate weights prescaled by log2e (2*log2e for g); rcpf activations.
// ---------------------------------------------------------------------------
__global__ __launch_bounds__(512, 4) void dec_mfma(
    const float* __restrict__ fused,
    const float* __restrict__ w_ih, const float* __restrict__ w_hh,
    const float* __restrict__ b_ih, const float* __restrict__ b_hh,
    const float* __restrict__ out_w, const float* __restrict__ out_b,
    float* __restrict__ out)
{
  __shared__ _Float16 h_lds[2][16][136];
  __shared__ float ow_lds[2][128];
  __shared__ float pred_lds[16][2];

  const int tid  = threadIdx.x;
  const int wv   = tid >> 6;
  const int lane = tid & 63;
  const int q    = lane >> 4;
  const int cb   = lane & 15;
  const long base = (long)blockIdx.x * 16;

  for (int i=tid;i<256;i+=512) ow_lds[i>>7][i&127] = out_w[i];
  for (int i=tid;i<2048;i+=512) h_lds[0][i>>7][i&127] = (_Float16)fused[base*128 + i];
  if (tid<32) pred_lds[tid>>1][tid&1] = 0.f;

  half8 bfrag[4][4];
  float bias_g[4], wi0[4], wi1[4];
  #pragma unroll
  for (int g=0; g<4; ++g){
    const float sc = (g==2) ? L2E2 : L2E;
    const int col = g*128 + wv*16 + cb;
    bias_g[g] = (b_ih[col] + b_hh[col])*sc;
    wi0[g] = w_ih[col*2+0]*sc;
    wi1[g] = w_ih[col*2+1]*sc;
    #pragma unroll
    for (int kc=0; kc<4; ++kc){
      const float* src = w_hh + (long)col*128 + kc*32 + q*8;
      half8 f;
      #pragma unroll
      for (int j=0;j<8;++j) f[j] = (_Float16)(src[j]*sc);
      bfrag[g][kc] = f;
    }
  }
  float ob0 = out_b[0], ob1 = out_b[1];
  __syncthreads();

  const int hcol = wv*16 + cb;
  float c_reg[4] = {0,0,0,0};
  float h_new[4];

  for (int t=0; t<25; ++t){
    const _Float16 (*hr)[136] = h_lds[t&1];
    _Float16 (*hw)[136]       = h_lds[(t+1)&1];

    floatx4 acc[4];
    #pragma unroll
    for (int r=0; r<4; ++r){
      float p0 = pred_lds[q*4+r][0], p1 = pred_lds[q*4+r][1];
      #pragma unroll
      for (int g=0; g<4; ++g)
        acc[g][r] = bias_g[g] + wi0[g]*p0 + wi1[g]*p1;
    }
    #pragma unroll
    for (int kc=0; kc<4; ++kc){
      half8 a = *(const half8*)&hr[cb][kc*32 + q*8];
      #pragma unroll
      for (int g=0; g<4; ++g)
        acc[g] = MFMA16(a, bfrag[g][kc], acc[g]);
    }
    #pragma unroll
    for (int r=0; r<4; ++r){
      float ig = sig_pre(acc[0][r]);
      float fg = sig_pre(acc[1][r]);
      float gg = tanh_pre(acc[2][r]);
      float og = sig_pre(acc[3][r]);
      float c  = fg*c_reg[r] + ig*gg;
      c_reg[r] = c;
      h_new[r] = og*tanh_raw(c);
    }
    #pragma unroll
    for (int r=0; r<4; ++r) hw[q*4+r][hcol] = (_Float16)h_new[r];
    __syncthreads();    // h(t+1) visible for projection + next step
    {
      int pair = tid>>3, part = tid&7;   // 32 pairs x 8 threads = 256
      if (pair < 32){
        int m = pair>>1, oc = pair&1;
        const float* owp = ow_lds[oc];
        float v = 0.f;
        #pragma unroll
        for (int k=part*16; k<part*16+16; ++k) v += owp[k]*(float)hw[m][k];
        v += __shfl_down(v, 4, 8);
        v += __shfl_down(v, 2, 8);
        v += __shfl_down(v, 1, 8);
        if (part==0){
          v += (oc ? ob1 : ob0);
          pred_lds[m][oc] = v;
          out[(base+m)*50 + t*2 + oc] = v;
        }
      }
    }
    __syncthreads();    // pred(t) visible for next step's acc init
  }
}

// ---------------------------------------------------------------------------
extern "C" void kernel_launch(void* const* d_in, const int* in_sizes, int n_in,
                              void* d_out, int out_size, void* d_ws, size_t ws_size,
                              hipStream_t stream)
{
  (void)in_sizes; (void)n_in; (void)out_size; (void)ws_size;
  const float* target   = (const float*)d_in[0];
  const float* neigh    = (const float*)d_in[1];
  const float* enc_w_ih = (const float*)d_in[4];
  const float* enc_w_hh = (const float*)d_in[5];
  const float* enc_b_ih = (const float*)d_in[6];
  const float* enc_b_hh = (const float*)d_in[7];
  const float* nb_w_ih  = (const float*)d_in[8];
  const float* nb_w_hh  = (const float*)d_in[9];
  const float* nb_b_ih  = (const float*)d_in[10];
  const float* nb_b_hh  = (const float*)d_in[11];
  const float* w1       = (const float*)d_in[12];
  const float* b1       = (const float*)d_in[13];
  const float* w2       = (const float*)d_in[14];
  const float* b2       = (const float*)d_in[15];
  const float* fus_w    = (const float*)d_in[16];
  const float* fus_b    = (const float*)d_in[17];
  const float* dec_w_ih = (const float*)d_in[18];
  const float* dec_w_hh = (const float*)d_in[19];
  const float* dec_b_ih = (const float*)d_in[20];
  const float* dec_b_hh = (const float*)d_in[21];
  const float* out_w    = (const float*)d_in[22];
  const float* out_b    = (const float*)d_in[23];

  char* ws = (char*)d_ws;
  _Float16* h_nb16  = (_Float16*)ws;                       // 16 MB
  _Float16* h_enc16 = (_Float16*)(ws + (16u<<20));         // 2 MB
  float*    fusedp  = (float*)(ws + (18u<<20));            // 4 MB
  char* aux = ws + (22u<<20);
  _Float16* w1f    = (_Float16*)aux;                       // 152,064 B
  _Float16* w2f    = (_Float16*)(aux + 152064);            // 39,168 B
  _Float16* fus_wf = (_Float16*)(aux + 152064 + 39168);    // 41,984 B
  float*    v2bg   = (float*)(aux + 233216);               // 8,192 B
  float*    bgmaxp = (float*)(aux + 241408);               // 128 B

  prep_kernel<<<64, 256, 0, stream>>>(w1, b1, w2, b2, fus_w, w1f, w2f, fus_wf, v2bg, bgmaxp);
  lstm_all<<<4608, 512, 0, stream>>>(target, neigh,
                                     enc_w_ih, enc_w_hh, enc_b_ih, enc_b_hh,
                                     nb_w_ih, nb_w_hh, nb_b_ih, nb_b_hh,
                                     h_enc16, h_nb16);
  social_fuse<<<512, 256, 0, stream>>>(h_enc16, h_nb16, w1f, w2f, fus_wf,
                                       b1, v2bg, bgmaxp, fus_b, fusedp);
  dec_mfma<<<512, 512, 0, stream>>>(fusedp, dec_w_ih, dec_w_hh, dec_b_ih, dec_b_hh,
                                    out_w, out_b, (float*)d_out);
}

// Round 8
// 554.252 us; speedup vs baseline: 1.0893x; 1.0893x over previous
//
#include <hip/hip_runtime.h>

typedef _Float16 half8  __attribute__((ext_vector_type(8)));
typedef _Float16 half4v __attribute__((ext_vector_type(4)));
typedef float  floatx4  __attribute__((ext_vector_type(4)));

#define MFMA16(A,B,C) __builtin_amdgcn_mfma_f32_16x16x32_f16((A),(B),(C),0,0,0)

#define L2E  1.4426950408889634f
#define L2E2 2.8853900817779268f

// prescaled-domain activations: y = L2E*x (sig) / 2*L2E*x (tanh). One exp2 +
// one rcp each (no fast-math in harness: plain / = full IEEE divide sequence).
__device__ __forceinline__ float sig_pre(float y){
  return __builtin_amdgcn_rcpf(1.0f + __builtin_amdgcn_exp2f(-y));
}
__device__ __forceinline__ float tanh_pre(float y){
  return 1.0f - 2.0f*__builtin_amdgcn_rcpf(1.0f + __builtin_amdgcn_exp2f(y));
}
__device__ __forceinline__ float tanh_raw(float c){
  return 1.0f - 2.0f*__builtin_amdgcn_rcpf(1.0f + __builtin_amdgcn_exp2f(L2E2*c));
}
// 8B-aligned f16x8 load (2x b64) — for LDS strides that are 8B- but not 16B-multiples
__device__ __forceinline__ half8 ld8(const _Float16* p){
  half4v a = *(const half4v*)p;
  half4v b = *(const half4v*)(p+4);
  return __builtin_shufflevector(a,b,0,1,2,3,4,5,6,7);
}

// grid geometry tables (compile-time foldable)
static __device__ constexpr int DY[27] = {0,0,0,0,0,0,0,0, 1,1,1,1,1,1,1,1, 2,2, 3,3,3,4,4,4,5,5,5};
static __device__ constexpr int DX[27] = {0,1,2,3,4,5,6,7, 0,1,2,3,4,5,6,7, 0,1, 3,4,5,3,4,5,3,4,5};
static __device__ constexpr int PY[9]  = {0,0,0,0,0,0,0,1,4};
static __device__ constexpr int PX[9]  = {1,2,3,4,5,6,7,0,4};
static __device__ constexpr int OY[46] = {0,0,0,0,0,0,0,0, 1,1,1,1,1,1,1,1, 2,2,2,2,2,2,2,2,
                                          3,3,3,3,3,3,3, 4,4,4,4,4, 5,5,5,5,5, 6,6,6,6,6};
static __device__ constexpr int OX[46] = {0,1,2,3,4,5,6,7, 0,1,2,3,4,5,6,7, 0,1,2,3,4,5,6,7,
                                          0,1,2,3,4,5,6, 2,3,4,5,6, 2,3,4,5,6, 2,3,4,5,6};
__device__ constexpr int d1idx(int iy,int ix){
  return (iy<0||iy>7||ix<0||ix>7) ? -1 :
         (iy<=1) ? iy*8+ix :
         (iy==2 && ix<=1) ? 16+ix :
         (iy>=3 && iy<=5 && ix>=3 && ix<=5) ? 18+(iy-3)*3+(ix-3) : -1;
}

// ---------------------------------------------------------------------------
// Combined encoder: blocks [0,512) = target LSTM, [512,4608) = neighbor LSTM.
// One block = 16 sequences (M=16), 8 waves; wave owns 16 hidden cols x 4 gates.
// Merged-K: K=160 in 5 chunks; kc0-3 = w_hh (regs), kc4 = [w_ih|bias] whose
// A-side is read DIRECTLY from xf16 (q==0) / a zero row (q!=0) — no per-step
// x-tail copy into h rows. a4(t+1) is PREFETCHED before the barrier (xf16 is
// read-only after staging → no hazard), so the 4 seed MFMAs issue immediately
// post-barrier while the h-dependent ds_reads are still in flight.
// ---------------------------------------------------------------------------
__global__ __launch_bounds__(512, 4) void lstm_all(
    const float* __restrict__ target, const float* __restrict__ neigh,
    const float* __restrict__ e_wih, const float* __restrict__ e_whh,
    const float* __restrict__ e_bih, const float* __restrict__ e_bhh,
    const float* __restrict__ n_wih, const float* __restrict__ n_whh,
    const float* __restrict__ n_bih, const float* __restrict__ n_bhh,
    _Float16* __restrict__ h_enc16, _Float16* __restrict__ h_nb16)
{
  __shared__ _Float16 h_lds[2][16][136];   // h only (128 + pad)
  __shared__ _Float16 xf16[16][168];       // [seq][t*8+f]; f==7 slot = 1.0 bias carrier; t=20 row zero
  __shared__ __align__(16) _Float16 wihb[8][4][17][8]; // [wave][gate][cb | row16=zeros][8]

  const int tid  = threadIdx.x;
  const int wv   = tid >> 6;
  const int lane = tid & 63;
  const int q    = lane >> 4;
  const int cb   = lane & 15;

  const bool enc = (blockIdx.x < 512);
  const float* x   = enc ? target : neigh;
  const float* wih = enc ? e_wih : n_wih;
  const float* whh = enc ? e_whh : n_whh;
  const float* bih = enc ? e_bih : n_bih;
  const float* bhh = enc ? e_bhh : n_bhh;
  _Float16* hout   = enc ? h_enc16 : h_nb16;
  const long base  = enc ? (long)blockIdx.x*16 : (long)(blockIdx.x-512)*16;

  for (int i = tid; i < 16*168; i += 512){
    int seq = i/168, rem = i%168, t = rem>>3, f = rem&7;
    float v = 0.f;
    if (t < 20) v = (f < 7) ? x[base*140 + seq*140 + t*7 + f] : 1.0f;
    xf16[seq][rem] = (_Float16)v;
  }
  for (int i = tid; i < 2*16*136; i += 512) ((_Float16*)h_lds)[i] = (_Float16)0.f;

  // per-wave w_ih|bias B-chunk into LDS (prescaled); row 16 = zeros
  if (q == 0){
    #pragma unroll
    for (int g=0; g<4; ++g){
      const float sc = (g==2) ? L2E2 : L2E;
      const int col = g*128 + wv*16 + cb;
      _Float16* d = &wihb[wv][g][cb][0];
      #pragma unroll
      for (int j=0;j<7;++j) d[j] = (_Float16)(wih[col*7+j]*sc);
      d[7] = (_Float16)((bih[col]+bhh[col])*sc);
    }
  } else if (lane == 16){
    #pragma unroll
    for (int g=0; g<4; ++g){
      _Float16* d = &wihb[wv][g][16][0];
      #pragma unroll
      for (int j=0;j<8;++j) d[j] = (_Float16)0.f;
    }
  }

  // w_hh B-frags in regs (prescaled): 4 gates x 4 chunks x 4 VGPR = 64 regs
  half8 bfrag[4][4];
  #pragma unroll
  for (int g=0; g<4; ++g){
    const float sc = (g==2) ? L2E2 : L2E;
    const int col = g*128 + wv*16 + cb;
    #pragma unroll
    for (int kc=0; kc<4; ++kc){
      const float* src = whh + (long)col*128 + kc*32 + q*8;
      half8 f;
      #pragma unroll
      for (int j=0;j<8;++j) f[j] = (_Float16)(src[j]*sc);
      bfrag[g][kc] = f;
    }
  }
  __syncthreads();

  const int hcol = wv*16 + cb;
  const _Float16* bxp = &wihb[wv][0][(q==0)?cb:16][0];  // gate stride = 136 f16
  const _Float16* a4p = (q==0) ? &xf16[cb][0] : &wihb[wv][0][16][0];
  const int a4step = (q==0) ? 8 : 0;                    // f16 units per step
  half8 a4 = *(const half8*)a4p;                        // x(0)|1.0 for q==0, zeros else
  a4p += a4step;

  float c_reg[4] = {0,0,0,0};
  float h_new[4] = {0,0,0,0};
  const floatx4 ZERO4 = {0.f,0.f,0.f,0.f};

  for (int t=0; t<20; ++t){
    const _Float16* hrow = &h_lds[t&1][cb][0];
    _Float16 (*hw)[136]  = h_lds[(t+1)&1];

    floatx4 acc[4];
    #pragma unroll
    for (int g=0; g<4; ++g){     // seed from prefetched a4 — no LDS dep
      half8 bx = *(const half8*)(bxp + g*136);
      acc[g] = MFMA16(a4, bx, ZERO4);
    }
    #pragma unroll
    for (int kc=0; kc<4; ++kc){
      half8 a = *(const half8*)(hrow + kc*32 + q*8);
      #pragma unroll
      for (int g=0; g<4; ++g)
        acc[g] = MFMA16(a, bfrag[g][kc], acc[g]);
    }
    #pragma unroll
    for (int r=0; r<4; ++r){
      float ig = sig_pre(acc[0][r]);
      float fg = sig_pre(acc[1][r]);
      float gg = tanh_pre(acc[2][r]);
      float og = sig_pre(acc[3][r]);
      float c  = fg*c_reg[r] + ig*gg;
      c_reg[r] = c;
      h_new[r] = og*tanh_raw(c);
    }
    #pragma unroll
    for (int r=0; r<4; ++r) hw[q*4 + r][hcol] = (_Float16)h_new[r];
    a4 = *(const half8*)a4p;     // prefetch x-chunk for t+1 (read-only LDS, safe pre-barrier)
    a4p += a4step;
    __syncthreads();
  }

  #pragma unroll
  for (int r=0; r<4; ++r)
    hout[(base + q*4 + r)*128 + hcol] = (_Float16)h_new[r];
}

// ---------------------------------------------------------------------------
// Prep: weights into MFMA B-fragment-friendly f16 layouts + conv2 background.
// ---------------------------------------------------------------------------
__global__ void prep_kernel(const float* __restrict__ w1, const float* __restrict__ b1,
                            const float* __restrict__ w2, const float* __restrict__ b2,
                            const float* __restrict__ fus_w,
                            _Float16* __restrict__ w1f, _Float16* __restrict__ w2f,
                            _Float16* __restrict__ fus_wf,
                            float* __restrict__ v2bg, float* __restrict__ bgmax)
{
  const int tid = threadIdx.x;
  const int gid = blockIdx.x*256 + tid;
  const int gstride = gridDim.x*256;
  for (int i = gid; i < 9*64*128; i += gstride){
    int s = i>>13, rem = i&8191, c1 = rem>>7, ci = rem&127;
    w1f[s*8448 + c1*132 + ci] = (_Float16)w1[c1*1152 + ci*9 + s];
  }
  for (int i = gid; i < 9*32*64; i += gstride){
    int s = i>>11, rem = i&2047, c2 = rem>>6, ci = rem&63;
    w2f[s*2176 + c2*68 + ci] = (_Float16)w2[c2*576 + ci*9 + s];
  }
  for (int i = gid; i < 128*160; i += gstride){
    int n = i/160, k = i%160;
    fus_wf[n*164 + k] = (_Float16)fus_w[i];
  }
  if (blockIdx.x == 0){
    __shared__ float S[288];
    __shared__ int bgm[32];
    for (int i=tid;i<288;i+=256){
      int c2=i/9, s=i%9;
      float a=0.f;
      for (int ci=0;ci<64;++ci) a += w2[c2*576+ci*9+s]*fmaxf(b1[ci],0.f);
      S[i]=a;
    }
    if (tid<32) bgm[tid]=0;
    __syncthreads();
    for (int i=tid;i<2048;i+=256){
      int cell=i>>5, c2=i&31, y=cell>>3, xx=cell&7;
      float a=b2[c2];
      for (int dy=0;dy<3;++dy){ int iy=y+dy-1; if((unsigned)iy>7u) continue;
        for (int dx=0;dx<3;++dx){ int ix=xx+dx-1; if((unsigned)ix>7u) continue;
          a += S[c2*9+dy*3+dx]; } }
      v2bg[cell*32+c2]=a;
      bool aff = (y<=2) || (y==3 && xx<=6) || (y>=4 && y<=6 && xx>=2 && xx<=6);
      if(!aff) atomicMax(&bgm[c2], __float_as_int(fmaxf(a,0.f)));
    }
    __syncthreads();
    if (tid<32) bgmax[tid]=__int_as_float(bgm[tid]);
  }
}

// ---------------------------------------------------------------------------
// Social pooling + sparse conv stack + maxpool + fusion, MFMA formulation.
// ---------------------------------------------------------------------------
__global__ __launch_bounds__(256, 1) void social_fuse(
    const _Float16* __restrict__ h_enc, const _Float16* __restrict__ h_nb,
    const _Float16* __restrict__ w1f, const _Float16* __restrict__ w2f,
    const _Float16* __restrict__ fus_wf,
    const float* __restrict__ b1, const float* __restrict__ v2bg,
    const float* __restrict__ bgmax, const float* __restrict__ fus_b,
    float* __restrict__ fused)
{
  __shared__ __align__(16) _Float16 vecs[9*16*132];
  __shared__ __align__(16) _Float16 d1[27*16*68];
  __shared__ __align__(16) _Float16 A16[16*164];
  __shared__ int pooled[512];

  const int tid  = threadIdx.x;
  const int wv   = tid >> 6;
  const int lane = tid & 63;
  const int q    = lane >> 4;
  const int cb   = lane & 15;
  const long base = (long)blockIdx.x * 16;

  for (int i=tid; i<9*16*32; i+=256){
    int p = i>>9, rem = i&511, bb = rem>>5, j = rem&31;
    const _Float16* src = (p<8) ? (h_nb + (((base+bb))*8 + p)*128 + j*4)
                                : (h_enc + (base+bb)*128 + j*4);
    *(unsigned long long*)(vecs + p*2112 + bb*132 + j*4) = *(const unsigned long long*)src;
  }
  for (int i=tid; i<512; i+=256){
    int bb=i>>5, j=i&31;
    *(unsigned long long*)(A16 + bb*164 + j*4) =
        *(const unsigned long long*)(h_enc + (base+bb)*128 + j*4);
  }
  for (int i=tid; i<512; i+=256) pooled[i] = __float_as_int(bgmax[i&31]);
  __syncthreads();

  {
    const int c1lane = wv*16 + cb;
    half8 bf1[9][4];
    #pragma unroll
    for (int s=0;s<9;++s)
      #pragma unroll
      for (int kc=0;kc<4;++kc)
        bf1[s][kc] = ld8(w1f + s*8448 + c1lane*132 + kc*32 + q*8);
    const float b1v = b1[c1lane];
    const float bg  = fmaxf(b1v, 0.f);

    #pragma unroll
    for (int ci=0; ci<27; ++ci){
      const int y = DY[ci], x = DX[ci];
      floatx4 C = {0.f,0.f,0.f,0.f};
      #pragma unroll
      for (int p=0;p<9;++p){
        const int dy = PY[p]-y+1, dx = PX[p]-x+1;
        if (dy>=0 && dy<3 && dx>=0 && dx<3){
          const int s = dy*3+dx;
          const _Float16* ap = vecs + p*2112 + cb*132 + q*8;
          #pragma unroll
          for (int kc=0;kc<4;++kc)
            C = MFMA16(ld8(ap + kc*32), bf1[s][kc], C);
        }
      }
      _Float16* dp = d1 + ci*1088 + c1lane;
      #pragma unroll
      for (int r=0;r<4;++r)
        dp[(q*4+r)*68] = (_Float16)(fmaxf(b1v + C[r], 0.f) - bg);
    }
  }
  __syncthreads();

  {
    half8 bf2[9][2][2];
    #pragma unroll
    for (int s=0;s<9;++s)
      #pragma unroll
      for (int nt=0;nt<2;++nt)
        #pragma unroll
        for (int kc=0;kc<2;++kc)
          bf2[s][nt][kc] = ld8(w2f + s*2176 + (nt*16+cb)*68 + kc*32 + q*8);

    float rm0[4] = {0,0,0,0}, rm1[4] = {0,0,0,0};
    #pragma unroll
    for (int oc=0; oc<46; ++oc){
      if ((oc & 3) != wv) continue;
      const int y = OY[oc], x = OX[oc];
      const int cell = y*8+x;
      float v0 = v2bg[cell*32 + cb];
      float v1 = v2bg[cell*32 + 16 + cb];
      floatx4 C0 = {v0,v0,v0,v0}, C1 = {v1,v1,v1,v1};
      #pragma unroll
      for (int dy=0;dy<3;++dy)
        #pragma unroll
        for (int dx=0;dx<3;++dx){
          const int dc = d1idx(y+dy-1, x+dx-1);
          if (dc < 0) continue;
          const int s = dy*3+dx;
          const _Float16* ap = d1 + dc*1088 + cb*68 + q*8;
          #pragma unroll
          for (int kc=0;kc<2;++kc){
            half8 a = ld8(ap + kc*32);
            C0 = MFMA16(a, bf2[s][0][kc], C0);
            C1 = MFMA16(a, bf2[s][1][kc], C1);
          }
        }
      #pragma unroll
      for (int r=0;r<4;++r){
        rm0[r] = fmaxf(rm0[r], fmaxf(C0[r],0.f));
        rm1[r] = fmaxf(rm1[r], fmaxf(C1[r],0.f));
      }
    }
    #pragma unroll
    for (int r=0;r<4;++r){
      atomicMax(&pooled[(q*4+r)*32 + cb],      __float_as_int(rm0[r]));
      atomicMax(&pooled[(q*4+r)*32 + 16 + cb], __float_as_int(rm1[r]));
    }
  }
  __syncthreads();

  for (int i=tid;i<512;i+=256){
    int bb=i>>5, c2=i&31;
    A16[bb*164 + 128 + c2] = (_Float16)__int_as_float(pooled[i]);
  }
  __syncthreads();

  {
    half8 bfF[2][5];
    #pragma unroll
    for (int nt2=0;nt2<2;++nt2)
      #pragma unroll
      for (int kc=0;kc<5;++kc)
        bfF[nt2][kc] = ld8(fus_wf + ((wv*2+nt2)*16+cb)*164 + kc*32 + q*8);
    const float fb0 = fus_b[(wv*2)*16+cb];
    const float fb1 = fus_b[(wv*2+1)*16+cb];
    floatx4 C0 = {0.f,0.f,0.f,0.f}, C1 = {0.f,0.f,0.f,0.f};
    #pragma unroll
    for (int kc=0;kc<5;++kc){
      half8 a = ld8(A16 + cb*164 + kc*32 + q*8);
      C0 = MFMA16(a, bfF[0][kc], C0);
      C1 = MFMA16(a, bfF[1][kc], C1);
    }
    #pragma unroll
    for (int r=0;r<4;++r){
      const long row = base + q*4 + r;
      fused[row*128 + (wv*2)*16+cb]   = tanh_raw(C0[r]+fb0);
      fused[row*128 + (wv*2+1)*16+cb] = tanh_raw(C1[r]+fb1);
    }
  }
}

// ---------------------------------------------------------------------------
// Decoder: 25 autoregressive steps. 16 seqs/block (M=16), 8 waves, 512 blocks.
// Gate weights prescaled by log2e (2*log2e for g); rcpf activations.
// ---------------------------------------------------------------------------
__global__ __launch_bounds__(512, 4) void dec_mfma(
    const float* __restrict__ fused,
    const float* __restrict__ w_ih, const float* __restrict__ w_hh,
    const float* __restrict__ b_ih, const float* __restrict__ b_hh,
    const float* __restrict__ out_w, const float* __restrict__ out_b,
    float* __restrict__ out)
{
  __shared__ _Float16 h_lds[2][16][136];
  __shared__ float ow_lds[2][128];
  __shared__ float pred_lds[16][2];

  const int tid  = threadIdx.x;
  const int wv   = tid >> 6;
  const int lane = tid & 63;
  const int q    = lane >> 4;
  const int cb   = lane & 15;
  const long base = (long)blockIdx.x * 16;

  for (int i=tid;i<256;i+=512) ow_lds[i>>7][i&127] = out_w[i];
  for (int i=tid;i<2048;i+=512) h_lds[0][i>>7][i&127] = (_Float16)fused[base*128 + i];
  if (tid<32) pred_lds[tid>>1][tid&1] = 0.f;

  half8 bfrag[4][4];
  float bias_g[4], wi0[4], wi1[4];
  #pragma unroll
  for (int g=0; g<4; ++g){
    const float sc = (g==2) ? L2E2 : L2E;
    const int col = g*128 + wv*16 + cb;
    bias_g[g] = (b_ih[col] + b_hh[col])*sc;
    wi0[g] = w_ih[col*2+0]*sc;
    wi1[g] = w_ih[col*2+1]*sc;
    #pragma unroll
    for (int kc=0; kc<4; ++kc){
      const float* src = w_hh + (long)col*128 + kc*32 + q*8;
      half8 f;
      #pragma unroll
      for (int j=0;j<8;++j) f[j] = (_Float16)(src[j]*sc);
      bfrag[g][kc] = f;
    }
  }
  float ob0 = out_b[0], ob1 = out_b[1];
  __syncthreads();

  const int hcol = wv*16 + cb;
  float c_reg[4] = {0,0,0,0};
  float h_new[4];

  for (int t=0; t<25; ++t){
    const _Float16 (*hr)[136] = h_lds[t&1];
    _Float16 (*hw)[136]       = h_lds[(t+1)&1];

    floatx4 acc[4];
    #pragma unroll
    for (int r=0; r<4; ++r){
      float p0 = pred_lds[q*4+r][0], p1 = pred_lds[q*4+r][1];
      #pragma unroll
      for (int g=0; g<4; ++g)
        acc[g][r] = bias_g[g] + wi0[g]*p0 + wi1[g]*p1;
    }
    #pragma unroll
    for (int kc=0; kc<4; ++kc){
      half8 a = *(const half8*)&hr[cb][kc*32 + q*8];
      #pragma unroll
      for (int g=0; g<4; ++g)
        acc[g] = MFMA16(a, bfrag[g][kc], acc[g]);
    }
    #pragma unroll
    for (int r=0; r<4; ++r){
      float ig = sig_pre(acc[0][r]);
      float fg = sig_pre(acc[1][r]);
      float gg = tanh_pre(acc[2][r]);
      float og = sig_pre(acc[3][r]);
      float c  = fg*c_reg[r] + ig*gg;
      c_reg[r] = c;
      h_new[r] = og*tanh_raw(c);
    }
    #pragma unroll
    for (int r=0; r<4; ++r) hw[q*4+r][hcol] = (_Float16)h_new[r];
    __syncthreads();    // h(t+1) visible for projection + next step
    {
      int pair = tid>>3, part = tid&7;   // 32 pairs x 8 threads = 256
      if (pair < 32){
        int m = pair>>1, oc = pair&1;
        const float* owp = ow_lds[oc];
        float v = 0.f;
        #pragma unroll
        for (int k=part*16; k<part*16+16; ++k) v += owp[k]*(float)hw[m][k];
        v += __shfl_down(v, 4, 8);
        v += __shfl_down(v, 2, 8);
        v += __shfl_down(v, 1, 8);
        if (part==0){
          v += (oc ? ob1 : ob0);
          pred_lds[m][oc] = v;
          out[(base+m)*50 + t*2 + oc] = v;
        }
      }
    }
    __syncthreads();    // pred(t) visible for next step's acc init
  }
}

// ---------------------------------------------------------------------------
extern "C" void kernel_launch(void* const* d_in, const int* in_sizes, int n_in,
                              void* d_out, int out_size, void* d_ws, size_t ws_size,
                              hipStream_t stream)
{
  (void)in_sizes; (void)n_in; (void)out_size; (void)ws_size;
  const float* target   = (const float*)d_in[0];
  const float* neigh    = (const float*)d_in[1];
  const float* enc_w_ih = (const float*)d_in[4];
  const float* enc_w_hh = (const float*)d_in[5];
  const float* enc_b_ih = (const float*)d_in[6];
  const float* enc_b_hh = (const float*)d_in[7];
  const float* nb_w_ih  = (const float*)d_in[8];
  const float* nb_w_hh  = (const float*)d_in[9];
  const float* nb_b_ih  = (const float*)d_in[10];
  const float* nb_b_hh  = (const float*)d_in[11];
  const float* w1       = (const float*)d_in[12];
  const float* b1       = (const float*)d_in[13];
  const float* w2       = (const float*)d_in[14];
  const float* b2       = (const float*)d_in[15];
  const float* fus_w    = (const float*)d_in[16];
  const float* fus_b    = (const float*)d_in[17];
  const float* dec_w_ih = (const float*)d_in[18];
  const float* dec_w_hh = (const float*)d_in[19];
  const float* dec_b_ih = (const float*)d_in[20];
  const float* dec_b_hh = (const float*)d_in[21];
  const float* out_w    = (const float*)d_in[22];
  const float* out_b    = (const float*)d_in[23];

  char* ws = (char*)d_ws;
  _Float16* h_nb16  = (_Float16*)ws;                       // 16 MB
  _Float16* h_enc16 = (_Float16*)(ws + (16u<<20));         // 2 MB
  float*    fusedp  = (float*)(ws + (18u<<20));            // 4 MB
  char* aux = ws + (22u<<20);
  _Float16* w1f    = (_Float16*)aux;                       // 152,064 B
  _Float16* w2f    = (_Float16*)(aux + 152064);            // 39,168 B
  _Float16* fus_wf = (_Float16*)(aux + 152064 + 39168);    // 41,984 B
  float*    v2bg   = (float*)(aux + 233216);               // 8,192 B
  float*    bgmaxp = (float*)(aux + 241408);               // 128 B

  prep_kernel<<<64, 256, 0, stream>>>(w1, b1, w2, b2, fus_w, w1f, w2f, fus_wf, v2bg, bgmaxp);
  lstm_all<<<4608, 512, 0, stream>>>(target, neigh,
                                     enc_w_ih, enc_w_hh, enc_b_ih, enc_b_hh,
                                     nb_w_ih, nb_w_hh, nb_b_ih, nb_b_hh,
                                     h_enc16, h_nb16);
  social_fuse<<<512, 256, 0, stream>>>(h_enc16, h_nb16, w1f, w2f, fus_wf,
                                       b1, v2bg, bgmaxp, fus_b, fusedp);
  dec_mfma<<<512, 512, 0, stream>>>(fusedp, dec_w_ih, dec_w_hh, dec_b_ih, dec_b_hh,
                                    out_w, out_b, (float*)d_out);
}

// Round 9
// 526.865 us; speedup vs baseline: 1.1459x; 1.0520x over previous
//
#include <hip/hip_runtime.h>

typedef _Float16 half8  __attribute__((ext_vector_type(8)));
typedef _Float16 half4v __attribute__((ext_vector_type(4)));
typedef float  floatx4  __attribute__((ext_vector_type(4)));

#define MFMA16(A,B,C) __builtin_amdgcn_mfma_f32_16x16x32_f16((A),(B),(C),0,0,0)

#define L2E  1.4426950408889634f
#define L2E2 2.8853900817779268f

__device__ __forceinline__ float rcpf(float x){ return __builtin_amdgcn_rcpf(x); }
__device__ __forceinline__ float ex2(float x){ return __builtin_amdgcn_exp2f(x); }
__device__ __forceinline__ float tanh_raw(float c){
  return 1.0f - 2.0f*rcpf(1.0f + ex2(L2E2*c));
}
// 8B-aligned f16x8 load (2x b64) — for LDS strides that are 8B- but not 16B-multiples
__device__ __forceinline__ half8 ld8(const _Float16* p){
  half4v a = *(const half4v*)p;
  half4v b = *(const half4v*)(p+4);
  return __builtin_shufflevector(a,b,0,1,2,3,4,5,6,7);
}

// Fused LSTM cell update (exact algebra, 8 trans instead of 10):
//  i=1/(1+A) f=1/(1+B) g=(C-1)/(C+1) o=1/(1+F) tanh(c')=(E-1)/(E+1)
//  c' = c/(1+B) + (C-1)/((1+A)(1+C));  h = (E-1)/((1+F)(1+E))
__device__ __forceinline__ float lstm_cell(float yi, float yf, float yg, float yo,
                                           float& c){
  float A = ex2(-yi), B = ex2(-yf), C = ex2(yg);
  float r1 = rcpf(1.0f + B);
  float r2 = rcpf((1.0f + A)*(1.0f + C));
  float cn = c*r1 + (C - 1.0f)*r2;
  c = cn;
  float F = ex2(-yo), E = ex2(L2E2*cn);
  float r3 = rcpf((1.0f + F)*(1.0f + E));
  return (E - 1.0f)*r3;
}

// grid geometry tables (compile-time foldable)
static __device__ constexpr int DY[27] = {0,0,0,0,0,0,0,0, 1,1,1,1,1,1,1,1, 2,2, 3,3,3,4,4,4,5,5,5};
static __device__ constexpr int DX[27] = {0,1,2,3,4,5,6,7, 0,1,2,3,4,5,6,7, 0,1, 3,4,5,3,4,5,3,4,5};
static __device__ constexpr int PY[9]  = {0,0,0,0,0,0,0,1,4};
static __device__ constexpr int PX[9]  = {1,2,3,4,5,6,7,0,4};
static __device__ constexpr int OY[46] = {0,0,0,0,0,0,0,0, 1,1,1,1,1,1,1,1, 2,2,2,2,2,2,2,2,
                                          3,3,3,3,3,3,3, 4,4,4,4,4, 5,5,5,5,5, 6,6,6,6,6};
static __device__ constexpr int OX[46] = {0,1,2,3,4,5,6,7, 0,1,2,3,4,5,6,7, 0,1,2,3,4,5,6,7,
                                          0,1,2,3,4,5,6, 2,3,4,5,6, 2,3,4,5,6, 2,3,4,5,6};
__device__ constexpr int d1idx(int iy,int ix){
  return (iy<0||iy>7||ix<0||ix>7) ? -1 :
         (iy<=1) ? iy*8+ix :
         (iy==2 && ix<=1) ? 16+ix :
         (iy>=3 && iy<=5 && ix>=3 && ix<=5) ? 18+(iy-3)*3+(ix-3) : -1;
}

// ---------------------------------------------------------------------------
// Combined encoder: blocks [0,512) = target, [512,4608) = neighbor LSTM.
// TRANSPOSED MFMA: D[m=hid][n=seq] via MFMA16(w_frag, h_frag, acc) — same
// register data and same LDS reads as before (A/B layouts symmetric), but each
// lane's 4 acc rows = 4 CONSECUTIVE hid for one seq → packed b64 h-writes.
// Merged-K: kc0-3 = w_hh (regs, A-side), seed = [w_ih|bias] (LDS A-chunk) ×
// x-chunk (prefetched B-frag from xf16; q!=0 lanes read a shared zero row).
// ---------------------------------------------------------------------------
__global__ __launch_bounds__(512, 4) void lstm_all(
    const float* __restrict__ target, const float* __restrict__ neigh,
    const float* __restrict__ e_wih, const float* __restrict__ e_whh,
    const float* __restrict__ e_bih, const float* __restrict__ e_bhh,
    const float* __restrict__ n_wih, const float* __restrict__ n_whh,
    const float* __restrict__ n_bih, const float* __restrict__ n_bhh,
    _Float16* __restrict__ h_enc16, _Float16* __restrict__ h_nb16)
{
  __shared__ _Float16 h_lds[2][16][136];   // [buf][seq][hid]
  __shared__ _Float16 xf16[16][168];       // [seq][t*8+f]; f==7 = 1.0 bias carrier; t=20 row zero
  __shared__ __align__(16) _Float16 wihb[8][4][17][8]; // [wave][gate][cb | row16=zeros][8]

  const int tid  = threadIdx.x;
  const int wv   = tid >> 6;
  const int lane = tid & 63;
  const int q    = lane >> 4;
  const int cb   = lane & 15;

  const bool enc = (blockIdx.x < 512);
  const float* x   = enc ? target : neigh;
  const float* wih = enc ? e_wih : n_wih;
  const float* whh = enc ? e_whh : n_whh;
  const float* bih = enc ? e_bih : n_bih;
  const float* bhh = enc ? e_bhh : n_bhh;
  _Float16* hout   = enc ? h_enc16 : h_nb16;
  const long base  = enc ? (long)blockIdx.x*16 : (long)(blockIdx.x-512)*16;

  for (int i = tid; i < 16*168; i += 512){
    int seq = i/168, rem = i%168, t = rem>>3, f = rem&7;
    float v = 0.f;
    if (t < 20) v = (f < 7) ? x[base*140 + seq*140 + t*7 + f] : 1.0f;
    xf16[seq][rem] = (_Float16)v;
  }
  for (int i = tid; i < 2*16*136; i += 512) ((_Float16*)h_lds)[i] = (_Float16)0.f;

  // per-wave w_ih|bias A-chunk into LDS (prescaled); row 16 = zeros
  if (q == 0){
    #pragma unroll
    for (int g=0; g<4; ++g){
      const float sc = (g==2) ? L2E2 : L2E;
      const int col = g*128 + wv*16 + cb;
      _Float16* d = &wihb[wv][g][cb][0];
      #pragma unroll
      for (int j=0;j<7;++j) d[j] = (_Float16)(wih[col*7+j]*sc);
      d[7] = (_Float16)((bih[col]+bhh[col])*sc);
    }
  } else if (lane == 16){
    #pragma unroll
    for (int g=0; g<4; ++g){
      _Float16* d = &wihb[wv][g][16][0];
      #pragma unroll
      for (int j=0;j<8;++j) d[j] = (_Float16)0.f;
    }
  }

  // w_hh fragments in regs (prescaled): 4 gates x 4 chunks x 4 VGPR = 64 regs
  half8 bfrag[4][4];
  #pragma unroll
  for (int g=0; g<4; ++g){
    const float sc = (g==2) ? L2E2 : L2E;
    const int col = g*128 + wv*16 + cb;
    #pragma unroll
    for (int kc=0; kc<4; ++kc){
      const float* src = whh + (long)col*128 + kc*32 + q*8;
      half8 f;
      #pragma unroll
      for (int j=0;j<8;++j) f[j] = (_Float16)(src[j]*sc);
      bfrag[g][kc] = f;
    }
  }
  __syncthreads();

  const _Float16* bxp = &wihb[wv][0][(q==0)?cb:16][0];  // gate stride = 136 f16
  const _Float16* a4p = (q==0) ? &xf16[cb][0] : &wihb[wv][0][16][0];
  const int a4step = (q==0) ? 8 : 0;
  half8 a4 = *(const half8*)a4p;                        // x(0)|1.0 (q==0) / zeros
  a4p += a4step;

  float c_reg[4] = {0,0,0,0};
  half4v hv = {0,0,0,0};
  const floatx4 ZERO4 = {0.f,0.f,0.f,0.f};

  for (int t=0; t<20; ++t){
    const _Float16* hrow = &h_lds[t&1][cb][0];

    floatx4 acc[4];
    #pragma unroll
    for (int g=0; g<4; ++g){     // seed: no LDS dep on h(t)
      half8 bx = *(const half8*)(bxp + g*136);
      acc[g] = MFMA16(bx, a4, ZERO4);
    }
    #pragma unroll
    for (int kc=0; kc<4; ++kc){
      half8 b = *(const half8*)(hrow + kc*32 + q*8);
      #pragma unroll
      for (int g=0; g<4; ++g)
        acc[g] = MFMA16(bfrag[g][kc], b, acc[g]);
    }
    #pragma unroll
    for (int r=0; r<4; ++r)
      hv[r] = (_Float16)lstm_cell(acc[0][r], acc[1][r], acc[2][r], acc[3][r], c_reg[r]);
    *(half4v*)&h_lds[(t+1)&1][cb][wv*16 + q*4] = hv;   // packed 8B write
    a4 = *(const half8*)a4p;     // prefetch x-chunk for t+1 (read-only LDS)
    a4p += a4step;
    __syncthreads();
  }

  *(half4v*)&hout[(base + cb)*128 + wv*16 + q*4] = hv;  // packed 8B store
}

// ---------------------------------------------------------------------------
// Prep: weights into MFMA B-fragment-friendly f16 layouts + conv2 background.
// ---------------------------------------------------------------------------
__global__ void prep_kernel(const float* __restrict__ w1, const float* __restrict__ b1,
                            const float* __restrict__ w2, const float* __restrict__ b2,
                            const float* __restrict__ fus_w,
                            _Float16* __restrict__ w1f, _Float16* __restrict__ w2f,
                            _Float16* __restrict__ fus_wf,
                            float* __restrict__ v2bg, float* __restrict__ bgmax)
{
  const int tid = threadIdx.x;
  const int gid = blockIdx.x*256 + tid;
  const int gstride = gridDim.x*256;
  for (int i = gid; i < 9*64*128; i += gstride){
    int s = i>>13, rem = i&8191, c1 = rem>>7, ci = rem&127;
    w1f[s*8448 + c1*132 + ci] = (_Float16)w1[c1*1152 + ci*9 + s];
  }
  for (int i = gid; i < 9*32*64; i += gstride){
    int s = i>>11, rem = i&2047, c2 = rem>>6, ci = rem&63;
    w2f[s*2176 + c2*68 + ci] = (_Float16)w2[c2*576 + ci*9 + s];
  }
  for (int i = gid; i < 128*160; i += gstride){
    int n = i/160, k = i%160;
    fus_wf[n*164 + k] = (_Float16)fus_w[i];
  }
  if (blockIdx.x == 0){
    __shared__ float S[288];
    __shared__ int bgm[32];
    for (int i=tid;i<288;i+=256){
      int c2=i/9, s=i%9;
      float a=0.f;
      for (int ci=0;ci<64;++ci) a += w2[c2*576+ci*9+s]*fmaxf(b1[ci],0.f);
      S[i]=a;
    }
    if (tid<32) bgm[tid]=0;
    __syncthreads();
    for (int i=tid;i<2048;i+=256){
      int cell=i>>5, c2=i&31, y=cell>>3, xx=cell&7;
      float a=b2[c2];
      for (int dy=0;dy<3;++dy){ int iy=y+dy-1; if((unsigned)iy>7u) continue;
        for (int dx=0;dx<3;++dx){ int ix=xx+dx-1; if((unsigned)ix>7u) continue;
          a += S[c2*9+dy*3+dx]; } }
      v2bg[cell*32+c2]=a;
      bool aff = (y<=2) || (y==3 && xx<=6) || (y>=4 && y<=6 && xx>=2 && xx<=6);
      if(!aff) atomicMax(&bgm[c2], __float_as_int(fmaxf(a,0.f)));
    }
    __syncthreads();
    if (tid<32) bgmax[tid]=__int_as_float(bgm[tid]);
  }
}

// ---------------------------------------------------------------------------
// Social pooling + sparse conv stack + maxpool + fusion, MFMA formulation.
// ---------------------------------------------------------------------------
__global__ __launch_bounds__(256, 1) void social_fuse(
    const _Float16* __restrict__ h_enc, const _Float16* __restrict__ h_nb,
    const _Float16* __restrict__ w1f, const _Float16* __restrict__ w2f,
    const _Float16* __restrict__ fus_wf,
    const float* __restrict__ b1, const float* __restrict__ v2bg,
    const float* __restrict__ bgmax, const float* __restrict__ fus_b,
    float* __restrict__ fused)
{
  __shared__ __align__(16) _Float16 vecs[9*16*132];
  __shared__ __align__(16) _Float16 d1[27*16*68];
  __shared__ __align__(16) _Float16 A16[16*164];
  __shared__ int pooled[512];

  const int tid  = threadIdx.x;
  const int wv   = tid >> 6;
  const int lane = tid & 63;
  const int q    = lane >> 4;
  const int cb   = lane & 15;
  const long base = (long)blockIdx.x * 16;

  for (int i=tid; i<9*16*32; i+=256){
    int p = i>>9, rem = i&511, bb = rem>>5, j = rem&31;
    const _Float16* src = (p<8) ? (h_nb + (((base+bb))*8 + p)*128 + j*4)
                                : (h_enc + (base+bb)*128 + j*4);
    *(unsigned long long*)(vecs + p*2112 + bb*132 + j*4) = *(const unsigned long long*)src;
  }
  for (int i=tid; i<512; i+=256){
    int bb=i>>5, j=i&31;
    *(unsigned long long*)(A16 + bb*164 + j*4) =
        *(const unsigned long long*)(h_enc + (base+bb)*128 + j*4);
  }
  for (int i=tid; i<512; i+=256) pooled[i] = __float_as_int(bgmax[i&31]);
  __syncthreads();

  {
    const int c1lane = wv*16 + cb;
    half8 bf1[9][4];
    #pragma unroll
    for (int s=0;s<9;++s)
      #pragma unroll
      for (int kc=0;kc<4;++kc)
        bf1[s][kc] = ld8(w1f + s*8448 + c1lane*132 + kc*32 + q*8);
    const float b1v = b1[c1lane];
    const float bg  = fmaxf(b1v, 0.f);

    #pragma unroll
    for (int ci=0; ci<27; ++ci){
      const int y = DY[ci], x = DX[ci];
      floatx4 C = {0.f,0.f,0.f,0.f};
      #pragma unroll
      for (int p=0;p<9;++p){
        const int dy = PY[p]-y+1, dx = PX[p]-x+1;
        if (dy>=0 && dy<3 && dx>=0 && dx<3){
          const int s = dy*3+dx;
          const _Float16* ap = vecs + p*2112 + cb*132 + q*8;
          #pragma unroll
          for (int kc=0;kc<4;++kc)
            C = MFMA16(ld8(ap + kc*32), bf1[s][kc], C);
        }
      }
      _Float16* dp = d1 + ci*1088 + c1lane;
      #pragma unroll
      for (int r=0;r<4;++r)
        dp[(q*4+r)*68] = (_Float16)(fmaxf(b1v + C[r], 0.f) - bg);
    }
  }
  __syncthreads();

  {
    half8 bf2[9][2][2];
    #pragma unroll
    for (int s=0;s<9;++s)
      #pragma unroll
      for (int nt=0;nt<2;++nt)
        #pragma unroll
        for (int kc=0;kc<2;++kc)
          bf2[s][nt][kc] = ld8(w2f + s*2176 + (nt*16+cb)*68 + kc*32 + q*8);

    float rm0[4] = {0,0,0,0}, rm1[4] = {0,0,0,0};
    #pragma unroll
    for (int oc=0; oc<46; ++oc){
      if ((oc & 3) != wv) continue;
      const int y = OY[oc], x = OX[oc];
      const int cell = y*8+x;
      float v0 = v2bg[cell*32 + cb];
      float v1 = v2bg[cell*32 + 16 + cb];
      floatx4 C0 = {v0,v0,v0,v0}, C1 = {v1,v1,v1,v1};
      #pragma unroll
      for (int dy=0;dy<3;++dy)
        #pragma unroll
        for (int dx=0;dx<3;++dx){
          const int dc = d1idx(y+dy-1, x+dx-1);
          if (dc < 0) continue;
          const int s = dy*3+dx;
          const _Float16* ap = d1 + dc*1088 + cb*68 + q*8;
          #pragma unroll
          for (int kc=0;kc<2;++kc){
            half8 a = ld8(ap + kc*32);
            C0 = MFMA16(a, bf2[s][0][kc], C0);
            C1 = MFMA16(a, bf2[s][1][kc], C1);
          }
        }
      #pragma unroll
      for (int r=0;r<4;++r){
        rm0[r] = fmaxf(rm0[r], fmaxf(C0[r],0.f));
        rm1[r] = fmaxf(rm1[r], fmaxf(C1[r],0.f));
      }
    }
    #pragma unroll
    for (int r=0;r<4;++r){
      atomicMax(&pooled[(q*4+r)*32 + cb],      __float_as_int(rm0[r]));
      atomicMax(&pooled[(q*4+r)*32 + 16 + cb], __float_as_int(rm1[r]));
    }
  }
  __syncthreads();

  for (int i=tid;i<512;i+=256){
    int bb=i>>5, c2=i&31;
    A16[bb*164 + 128 + c2] = (_Float16)__int_as_float(pooled[i]);
  }
  __syncthreads();

  {
    half8 bfF[2][5];
    #pragma unroll
    for (int nt2=0;nt2<2;++nt2)
      #pragma unroll
      for (int kc=0;kc<5;++kc)
        bfF[nt2][kc] = ld8(fus_wf + ((wv*2+nt2)*16+cb)*164 + kc*32 + q*8);
    const float fb0 = fus_b[(wv*2)*16+cb];
    const float fb1 = fus_b[(wv*2+1)*16+cb];
    floatx4 C0 = {0.f,0.f,0.f,0.f}, C1 = {0.f,0.f,0.f,0.f};
    #pragma unroll
    for (int kc=0;kc<5;++kc){
      half8 a = ld8(A16 + cb*164 + kc*32 + q*8);
      C0 = MFMA16(a, bfF[0][kc], C0);
      C1 = MFMA16(a, bfF[1][kc], C1);
    }
    #pragma unroll
    for (int r=0;r<4;++r){
      const long row = base + q*4 + r;
      fused[row*128 + (wv*2)*16+cb]   = tanh_raw(C0[r]+fb0);
      fused[row*128 + (wv*2+1)*16+cb] = tanh_raw(C1[r]+fb1);
    }
  }
}

// ---------------------------------------------------------------------------
// Decoder: 25 autoregressive steps, transposed MFMA like lstm_all.
// Seed MFMA: A = [wi0|wi1|bias] LDS chunk, B = [p0,p1,1] built per step.
// ---------------------------------------------------------------------------
__global__ __launch_bounds__(512, 4) void dec_mfma(
    const float* __restrict__ fused,
    const float* __restrict__ w_ih, const float* __restrict__ w_hh,
    const float* __restrict__ b_ih, const float* __restrict__ b_hh,
    const float* __restrict__ out_w, const float* __restrict__ out_b,
    float* __restrict__ out)
{
  __shared__ _Float16 h_lds[2][16][136];
  __shared__ __align__(16) _Float16 wib[8][4][17][8]; // [wave][gate][cb | row16=zeros][8]
  __shared__ float ow_lds[2][128];
  __shared__ float pred_lds[16][2];

  const int tid  = threadIdx.x;
  const int wv   = tid >> 6;
  const int lane = tid & 63;
  const int q    = lane >> 4;
  const int cb   = lane & 15;
  const long base = (long)blockIdx.x * 16;

  for (int i=tid;i<256;i+=512) ow_lds[i>>7][i&127] = out_w[i];
  for (int i=tid;i<2048;i+=512) h_lds[0][i>>7][i&127] = (_Float16)fused[base*128 + i];
  for (int i=tid;i<2048;i+=512) h_lds[1][i>>7][i&127] = (_Float16)0.f;
  if (tid<32) pred_lds[tid>>1][tid&1] = 0.f;

  if (q == 0){
    #pragma unroll
    for (int g=0; g<4; ++g){
      const float sc = (g==2) ? L2E2 : L2E;
      const int col = g*128 + wv*16 + cb;
      _Float16* d = &wib[wv][g][cb][0];
      d[0] = (_Float16)(w_ih[col*2+0]*sc);
      d[1] = (_Float16)(w_ih[col*2+1]*sc);
      d[2] = (_Float16)((b_ih[col]+b_hh[col])*sc);
      #pragma unroll
      for (int j=3;j<8;++j) d[j] = (_Float16)0.f;
    }
  } else if (lane == 16){
    #pragma unroll
    for (int g=0; g<4; ++g){
      _Float16* d = &wib[wv][g][16][0];
      #pragma unroll
      for (int j=0;j<8;++j) d[j] = (_Float16)0.f;
    }
  }

  half8 bfrag[4][4];
  #pragma unroll
  for (int g=0; g<4; ++g){
    const float sc = (g==2) ? L2E2 : L2E;
    const int col = g*128 + wv*16 + cb;
    #pragma unroll
    for (int kc=0; kc<4; ++kc){
      const float* src = w_hh + (long)col*128 + kc*32 + q*8;
      half8 f;
      #pragma unroll
      for (int j=0;j<8;++j) f[j] = (_Float16)(src[j]*sc);
      bfrag[g][kc] = f;
    }
  }
  float ob0 = out_b[0], ob1 = out_b[1];
  __syncthreads();

  const _Float16* wibp = &wib[wv][0][(q==0)?cb:16][0];  // gate stride = 136 f16
  float c_reg[4] = {0,0,0,0};
  half4v hv;
  const floatx4 ZERO4 = {0.f,0.f,0.f,0.f};

  for (int t=0; t<25; ++t){
    const _Float16* hrow = &h_lds[t&1][cb][0];

    half8 pb = {0,0,0,0,0,0,0,0};   // B-frag [p0,p1,1,0..] for seq=cb (q==0)
    if (q == 0){
      pb[0] = (_Float16)pred_lds[cb][0];
      pb[1] = (_Float16)pred_lds[cb][1];
      pb[2] = (_Float16)1.0f;
    }
    floatx4 acc[4];
    #pragma unroll
    for (int g=0; g<4; ++g){
      half8 w = *(const half8*)(wibp + g*136);
      acc[g] = MFMA16(w, pb, ZERO4);
    }
    #pragma unroll
    for (int kc=0; kc<4; ++kc){
      half8 b = *(const half8*)(hrow + kc*32 + q*8);
      #pragma unroll
      for (int g=0; g<4; ++g)
        acc[g] = MFMA16(bfrag[g][kc], b, acc[g]);
    }
    #pragma unroll
    for (int r=0; r<4; ++r)
      hv[r] = (_Float16)lstm_cell(acc[0][r], acc[1][r], acc[2][r], acc[3][r], c_reg[r]);
    _Float16 (*hw)[136] = h_lds[(t+1)&1];
    *(half4v*)&hw[cb][wv*16 + q*4] = hv;
    __syncthreads();    // h(t+1) visible for projection + next step
    {
      int pair = tid>>3, part = tid&7;   // 32 pairs x 8 threads = 256
      if (pair < 32){
        int m = pair>>1, oc = pair&1;
        const float* owp = ow_lds[oc];
        float v = 0.f;
        #pragma unroll
        for (int k=part*16; k<part*16+16; ++k) v += owp[k]*(float)hw[m][k];
        v += __shfl_down(v, 4, 8);
        v += __shfl_down(v, 2, 8);
        v += __shfl_down(v, 1, 8);
        if (part==0){
          v += (oc ? ob1 : ob0);
          pred_lds[m][oc] = v;
          out[(base+m)*50 + t*2 + oc] = v;
        }
      }
    }
    __syncthreads();    // pred(t) visible for next step's seed
  }
}

// ---------------------------------------------------------------------------
extern "C" void kernel_launch(void* const* d_in, const int* in_sizes, int n_in,
                              void* d_out, int out_size, void* d_ws, size_t ws_size,
                              hipStream_t stream)
{
  (void)in_sizes; (void)n_in; (void)out_size; (void)ws_size;
  const float* target   = (const float*)d_in[0];
  const float* neigh    = (const float*)d_in[1];
  const float* enc_w_ih = (const float*)d_in[4];
  const float* enc_w_hh = (const float*)d_in[5];
  const float* enc_b_ih = (const float*)d_in[6];
  const float* enc_b_hh = (const float*)d_in[7];
  const float* nb_w_ih  = (const float*)d_in[8];
  const float* nb_w_hh  = (const float*)d_in[9];
  const float* nb_b_ih  = (const float*)d_in[10];
  const float* nb_b_hh  = (const float*)d_in[11];
  const float* w1       = (const float*)d_in[12];
  const float* b1       = (const float*)d_in[13];
  const float* w2       = (const float*)d_in[14];
  const float* b2       = (const float*)d_in[15];
  const float* fus_w    = (const float*)d_in[16];
  const float* fus_b    = (const float*)d_in[17];
  const float* dec_w_ih = (const float*)d_in[18];
  const float* dec_w_hh = (const float*)d_in[19];
  const float* dec_b_ih = (const float*)d_in[20];
  const float* dec_b_hh = (const float*)d_in[21];
  const float* out_w    = (const float*)d_in[22];
  const float* out_b    = (const float*)d_in[23];

  char* ws = (char*)d_ws;
  _Float16* h_nb16  = (_Float16*)ws;                       // 16 MB
  _Float16* h_enc16 = (_Float16*)(ws + (16u<<20));         // 2 MB
  float*    fusedp  = (float*)(ws + (18u<<20));            // 4 MB
  char* aux = ws + (22u<<20);
  _Float16* w1f    = (_Float16*)aux;                       // 152,064 B
  _Float16* w2f    = (_Float16*)(aux + 152064);            // 39,168 B
  _Float16* fus_wf = (_Float16*)(aux + 152064 + 39168);    // 41,984 B
  float*    v2bg   = (float*)(aux + 233216);               // 8,192 B
  float*    bgmaxp = (float*)(aux + 241408);               // 128 B

  prep_kernel<<<64, 256, 0, stream>>>(w1, b1, w2, b2, fus_w, w1f, w2f, fus_wf, v2bg, bgmaxp);
  lstm_all<<<4608, 512, 0, stream>>>(target, neigh,
                                     enc_w_ih, enc_w_hh, enc_b_ih, enc_b_hh,
                                     nb_w_ih, nb_w_hh, nb_b_ih, nb_b_hh,
                                     h_enc16, h_nb16);
  social_fuse<<<512, 256, 0, stream>>>(h_enc16, h_nb16, w1f, w2f, fus_wf,
                                       b1, v2bg, bgmaxp, fus_b, fusedp);
  dec_mfma<<<512, 512, 0, stream>>>(fusedp, dec_w_ih, dec_w_hh, dec_b_ih, dec_b_hh,
                                    out_w, out_b, (float*)d_out);
}

// Round 10
// 505.511 us; speedup vs baseline: 1.1943x; 1.0422x over previous
//
#include <hip/hip_runtime.h>

typedef _Float16 half8  __attribute__((ext_vector_type(8)));
typedef _Float16 half4v __attribute__((ext_vector_type(4)));
typedef float  floatx4  __attribute__((ext_vector_type(4)));

#define MFMA16(A,B,C) __builtin_amdgcn_mfma_f32_16x16x32_f16((A),(B),(C),0,0,0)

#define L2E  1.4426950408889634f
#define L2E2 2.8853900817779268f

__device__ __forceinline__ float rcpf(float x){ return __builtin_amdgcn_rcpf(x); }
__device__ __forceinline__ float ex2(float x){ return __builtin_amdgcn_exp2f(x); }
__device__ __forceinline__ float tanh_raw(float c){
  return 1.0f - 2.0f*rcpf(1.0f + ex2(L2E2*c));
}
__device__ __forceinline__ half8 ld8(const _Float16* p){
  half4v a = *(const half4v*)p;
  half4v b = *(const half4v*)(p+4);
  return __builtin_shufflevector(a,b,0,1,2,3,4,5,6,7);
}

// Fused LSTM cell (exact algebra, 8 trans): c'=c/(1+B)+(C-1)/((1+A)(1+C));
// h=(E-1)/((1+F)(1+E)) with A=2^-yi B=2^-yf C=2^yg F=2^-yo E=2^(2L c').
__device__ __forceinline__ float lstm_cell(float yi, float yf, float yg, float yo,
                                           float& c){
  float A = ex2(-yi), B = ex2(-yf), C = ex2(yg);
  float r1 = rcpf(1.0f + B);
  float r2 = rcpf((1.0f + A)*(1.0f + C));
  float cn = c*r1 + (C - 1.0f)*r2;
  c = cn;
  float F = ex2(-yo), E = ex2(L2E2*cn);
  float r3 = rcpf((1.0f + F)*(1.0f + E));
  return (E - 1.0f)*r3;
}

// grid geometry tables (compile-time foldable)
static __device__ constexpr int DY[27] = {0,0,0,0,0,0,0,0, 1,1,1,1,1,1,1,1, 2,2, 3,3,3,4,4,4,5,5,5};
static __device__ constexpr int DX[27] = {0,1,2,3,4,5,6,7, 0,1,2,3,4,5,6,7, 0,1, 3,4,5,3,4,5,3,4,5};
static __device__ constexpr int PY[9]  = {0,0,0,0,0,0,0,1,4};
static __device__ constexpr int PX[9]  = {1,2,3,4,5,6,7,0,4};
static __device__ constexpr int OY[46] = {0,0,0,0,0,0,0,0, 1,1,1,1,1,1,1,1, 2,2,2,2,2,2,2,2,
                                          3,3,3,3,3,3,3, 4,4,4,4,4, 5,5,5,5,5, 6,6,6,6,6};
static __device__ constexpr int OX[46] = {0,1,2,3,4,5,6,7, 0,1,2,3,4,5,6,7, 0,1,2,3,4,5,6,7,
                                          0,1,2,3,4,5,6, 2,3,4,5,6, 2,3,4,5,6, 2,3,4,5,6};
__device__ constexpr int d1idx(int iy,int ix){
  return (iy<0||iy>7||ix<0||ix>7) ? -1 :
         (iy<=1) ? iy*8+ix :
         (iy==2 && ix<=1) ? 16+ix :
         (iy>=3 && iy<=5 && ix>=3 && ix<=5) ? 18+(iy-3)*3+(ix-3) : -1;
}

// ---------------------------------------------------------------------------
// Combined encoder (unchanged from R8): transposed MFMA, merged-K, 1 barrier.
// ---------------------------------------------------------------------------
__global__ __launch_bounds__(512, 4) void lstm_all(
    const float* __restrict__ target, const float* __restrict__ neigh,
    const float* __restrict__ e_wih, const float* __restrict__ e_whh,
    const float* __restrict__ e_bih, const float* __restrict__ e_bhh,
    const float* __restrict__ n_wih, const float* __restrict__ n_whh,
    const float* __restrict__ n_bih, const float* __restrict__ n_bhh,
    _Float16* __restrict__ h_enc16, _Float16* __restrict__ h_nb16)
{
  __shared__ _Float16 h_lds[2][16][136];
  __shared__ _Float16 xf16[16][168];
  __shared__ __align__(16) _Float16 wihb[8][4][17][8];

  const int tid  = threadIdx.x;
  const int wv   = tid >> 6;
  const int lane = tid & 63;
  const int q    = lane >> 4;
  const int cb   = lane & 15;

  const bool enc = (blockIdx.x < 512);
  const float* x   = enc ? target : neigh;
  const float* wih = enc ? e_wih : n_wih;
  const float* whh = enc ? e_whh : n_whh;
  const float* bih = enc ? e_bih : n_bih;
  const float* bhh = enc ? e_bhh : n_bhh;
  _Float16* hout   = enc ? h_enc16 : h_nb16;
  const long base  = enc ? (long)blockIdx.x*16 : (long)(blockIdx.x-512)*16;

  for (int i = tid; i < 16*168; i += 512){
    int seq = i/168, rem = i%168, t = rem>>3, f = rem&7;
    float v = 0.f;
    if (t < 20) v = (f < 7) ? x[base*140 + seq*140 + t*7 + f] : 1.0f;
    xf16[seq][rem] = (_Float16)v;
  }
  for (int i = tid; i < 2*16*136; i += 512) ((_Float16*)h_lds)[i] = (_Float16)0.f;

  if (q == 0){
    #pragma unroll
    for (int g=0; g<4; ++g){
      const float sc = (g==2) ? L2E2 : L2E;
      const int col = g*128 + wv*16 + cb;
      _Float16* d = &wihb[wv][g][cb][0];
      #pragma unroll
      for (int j=0;j<7;++j) d[j] = (_Float16)(wih[col*7+j]*sc);
      d[7] = (_Float16)((bih[col]+bhh[col])*sc);
    }
  } else if (lane == 16){
    #pragma unroll
    for (int g=0; g<4; ++g){
      _Float16* d = &wihb[wv][g][16][0];
      #pragma unroll
      for (int j=0;j<8;++j) d[j] = (_Float16)0.f;
    }
  }

  half8 bfrag[4][4];
  #pragma unroll
  for (int g=0; g<4; ++g){
    const float sc = (g==2) ? L2E2 : L2E;
    const int col = g*128 + wv*16 + cb;
    #pragma unroll
    for (int kc=0; kc<4; ++kc){
      const float* src = whh + (long)col*128 + kc*32 + q*8;
      half8 f;
      #pragma unroll
      for (int j=0;j<8;++j) f[j] = (_Float16)(src[j]*sc);
      bfrag[g][kc] = f;
    }
  }
  __syncthreads();

  const _Float16* bxp = &wihb[wv][0][(q==0)?cb:16][0];
  const _Float16* a4p = (q==0) ? &xf16[cb][0] : &wihb[wv][0][16][0];
  const int a4step = (q==0) ? 8 : 0;
  half8 a4 = *(const half8*)a4p;
  a4p += a4step;

  float c_reg[4] = {0,0,0,0};
  half4v hv = {0,0,0,0};
  const floatx4 ZERO4 = {0.f,0.f,0.f,0.f};

  for (int t=0; t<20; ++t){
    const _Float16* hrow = &h_lds[t&1][cb][0];

    floatx4 acc[4];
    #pragma unroll
    for (int g=0; g<4; ++g){
      half8 bx = *(const half8*)(bxp + g*136);
      acc[g] = MFMA16(bx, a4, ZERO4);
    }
    #pragma unroll
    for (int kc=0; kc<4; ++kc){
      half8 b = *(const half8*)(hrow + kc*32 + q*8);
      #pragma unroll
      for (int g=0; g<4; ++g)
        acc[g] = MFMA16(bfrag[g][kc], b, acc[g]);
    }
    #pragma unroll
    for (int r=0; r<4; ++r)
      hv[r] = (_Float16)lstm_cell(acc[0][r], acc[1][r], acc[2][r], acc[3][r], c_reg[r]);
    *(half4v*)&h_lds[(t+1)&1][cb][wv*16 + q*4] = hv;
    a4 = *(const half8*)a4p;
    a4p += a4step;
    __syncthreads();
  }

  *(half4v*)&hout[(base + cb)*128 + wv*16 + q*4] = hv;
}

// ---------------------------------------------------------------------------
// Prep: conv/fusion weight layouts + conv2 background + DECODER FOLD:
//   whhp = (dec_whh + dec_wih @ out_w) * sc   (f16, prescaled)
//   biasp = (dec_bih + dec_bhh + dec_wih @ out_b) * sc   (f32)
// ---------------------------------------------------------------------------
__global__ void prep_kernel(const float* __restrict__ w1, const float* __restrict__ b1,
                            const float* __restrict__ w2, const float* __restrict__ b2,
                            const float* __restrict__ fus_w,
                            const float* __restrict__ dec_wih, const float* __restrict__ dec_whh,
                            const float* __restrict__ dec_bih, const float* __restrict__ dec_bhh,
                            const float* __restrict__ out_w, const float* __restrict__ out_b,
                            _Float16* __restrict__ w1f, _Float16* __restrict__ w2f,
                            _Float16* __restrict__ fus_wf,
                            _Float16* __restrict__ whhp, float* __restrict__ biasp,
                            float* __restrict__ v2bg, float* __restrict__ bgmax)
{
  const int tid = threadIdx.x;
  const int gid = blockIdx.x*256 + tid;
  const int gstride = gridDim.x*256;
  for (int i = gid; i < 9*64*128; i += gstride){
    int s = i>>13, rem = i&8191, c1 = rem>>7, ci = rem&127;
    w1f[s*8448 + c1*132 + ci] = (_Float16)w1[c1*1152 + ci*9 + s];
  }
  for (int i = gid; i < 9*32*64; i += gstride){
    int s = i>>11, rem = i&2047, c2 = rem>>6, ci = rem&63;
    w2f[s*2176 + c2*68 + ci] = (_Float16)w2[c2*576 + ci*9 + s];
  }
  for (int i = gid; i < 128*160; i += gstride){
    int n = i/160, k = i%160;
    fus_wf[n*164 + k] = (_Float16)fus_w[i];
  }
  for (int i = gid; i < 512*128; i += gstride){
    int col = i>>7, k = i&127;
    float sc = ((col>>7)==2) ? L2E2 : L2E;
    float v = dec_whh[i] + dec_wih[col*2+0]*out_w[k] + dec_wih[col*2+1]*out_w[128+k];
    whhp[i] = (_Float16)(v*sc);
  }
  for (int i = gid; i < 512; i += gstride){
    float sc = ((i>>7)==2) ? L2E2 : L2E;
    biasp[i] = (dec_bih[i] + dec_bhh[i] + dec_wih[i*2+0]*out_b[0]
                + dec_wih[i*2+1]*out_b[1])*sc;
  }
  if (blockIdx.x == 0){
    __shared__ float S[288];
    __shared__ int bgm[32];
    for (int i=tid;i<288;i+=256){
      int c2=i/9, s=i%9;
      float a=0.f;
      for (int ci=0;ci<64;++ci) a += w2[c2*576+ci*9+s]*fmaxf(b1[ci],0.f);
      S[i]=a;
    }
    if (tid<32) bgm[tid]=0;
    __syncthreads();
    for (int i=tid;i<2048;i+=256){
      int cell=i>>5, c2=i&31, y=cell>>3, xx=cell&7;
      float a=b2[c2];
      for (int dy=0;dy<3;++dy){ int iy=y+dy-1; if((unsigned)iy>7u) continue;
        for (int dx=0;dx<3;++dx){ int ix=xx+dx-1; if((unsigned)ix>7u) continue;
          a += S[c2*9+dy*3+dx]; } }
      v2bg[cell*32+c2]=a;
      bool aff = (y<=2) || (y==3 && xx<=6) || (y>=4 && y<=6 && xx>=2 && xx<=6);
      if(!aff) atomicMax(&bgm[c2], __float_as_int(fmaxf(a,0.f)));
    }
    __syncthreads();
    if (tid<32) bgmax[tid]=__int_as_float(bgm[tid]);
  }
}

// ---------------------------------------------------------------------------
// Social pooling + sparse conv stack + maxpool + fusion (unchanged from R8).
// ---------------------------------------------------------------------------
__global__ __launch_bounds__(256, 1) void social_fuse(
    const _Float16* __restrict__ h_enc, const _Float16* __restrict__ h_nb,
    const _Float16* __restrict__ w1f, const _Float16* __restrict__ w2f,
    const _Float16* __restrict__ fus_wf,
    const float* __restrict__ b1, const float* __restrict__ v2bg,
    const float* __restrict__ bgmax, const float* __restrict__ fus_b,
    float* __restrict__ fused)
{
  __shared__ __align__(16) _Float16 vecs[9*16*132];
  __shared__ __align__(16) _Float16 d1[27*16*68];
  __shared__ __align__(16) _Float16 A16[16*164];
  __shared__ int pooled[512];

  const int tid  = threadIdx.x;
  const int wv   = tid >> 6;
  const int lane = tid & 63;
  const int q    = lane >> 4;
  const int cb   = lane & 15;
  const long base = (long)blockIdx.x * 16;

  for (int i=tid; i<9*16*32; i+=256){
    int p = i>>9, rem = i&511, bb = rem>>5, j = rem&31;
    const _Float16* src = (p<8) ? (h_nb + (((base+bb))*8 + p)*128 + j*4)
                                : (h_enc + (base+bb)*128 + j*4);
    *(unsigned long long*)(vecs + p*2112 + bb*132 + j*4) = *(const unsigned long long*)src;
  }
  for (int i=tid; i<512; i+=256){
    int bb=i>>5, j=i&31;
    *(unsigned long long*)(A16 + bb*164 + j*4) =
        *(const unsigned long long*)(h_enc + (base+bb)*128 + j*4);
  }
  for (int i=tid; i<512; i+=256) pooled[i] = __float_as_int(bgmax[i&31]);
  __syncthreads();

  {
    const int c1lane = wv*16 + cb;
    half8 bf1[9][4];
    #pragma unroll
    for (int s=0;s<9;++s)
      #pragma unroll
      for (int kc=0;kc<4;++kc)
        bf1[s][kc] = ld8(w1f + s*8448 + c1lane*132 + kc*32 + q*8);
    const float b1v = b1[c1lane];
    const float bg  = fmaxf(b1v, 0.f);

    #pragma unroll
    for (int ci=0; ci<27; ++ci){
      const int y = DY[ci], x = DX[ci];
      floatx4 C = {0.f,0.f,0.f,0.f};
      #pragma unroll
      for (int p=0;p<9;++p){
        const int dy = PY[p]-y+1, dx = PX[p]-x+1;
        if (dy>=0 && dy<3 && dx>=0 && dx<3){
          const int s = dy*3+dx;
          const _Float16* ap = vecs + p*2112 + cb*132 + q*8;
          #pragma unroll
          for (int kc=0;kc<4;++kc)
            C = MFMA16(ld8(ap + kc*32), bf1[s][kc], C);
        }
      }
      _Float16* dp = d1 + ci*1088 + c1lane;
      #pragma unroll
      for (int r=0;r<4;++r)
        dp[(q*4+r)*68] = (_Float16)(fmaxf(b1v + C[r], 0.f) - bg);
    }
  }
  __syncthreads();

  {
    half8 bf2[9][2][2];
    #pragma unroll
    for (int s=0;s<9;++s)
      #pragma unroll
      for (int nt=0;nt<2;++nt)
        #pragma unroll
        for (int kc=0;kc<2;++kc)
          bf2[s][nt][kc] = ld8(w2f + s*2176 + (nt*16+cb)*68 + kc*32 + q*8);

    float rm0[4] = {0,0,0,0}, rm1[4] = {0,0,0,0};
    #pragma unroll
    for (int oc=0; oc<46; ++oc){
      if ((oc & 3) != wv) continue;
      const int y = OY[oc], x = OX[oc];
      const int cell = y*8+x;
      float v0 = v2bg[cell*32 + cb];
      float v1 = v2bg[cell*32 + 16 + cb];
      floatx4 C0 = {v0,v0,v0,v0}, C1 = {v1,v1,v1,v1};
      #pragma unroll
      for (int dy=0;dy<3;++dy)
        #pragma unroll
        for (int dx=0;dx<3;++dx){
          const int dc = d1idx(y+dy-1, x+dx-1);
          if (dc < 0) continue;
          const int s = dy*3+dx;
          const _Float16* ap = d1 + dc*1088 + cb*68 + q*8;
          #pragma unroll
          for (int kc=0;kc<2;++kc){
            half8 a = ld8(ap + kc*32);
            C0 = MFMA16(a, bf2[s][0][kc], C0);
            C1 = MFMA16(a, bf2[s][1][kc], C1);
          }
        }
      #pragma unroll
      for (int r=0;r<4;++r){
        rm0[r] = fmaxf(rm0[r], fmaxf(C0[r],0.f));
        rm1[r] = fmaxf(rm1[r], fmaxf(C1[r],0.f));
      }
    }
    #pragma unroll
    for (int r=0;r<4;++r){
      atomicMax(&pooled[(q*4+r)*32 + cb],      __float_as_int(rm0[r]));
      atomicMax(&pooled[(q*4+r)*32 + 16 + cb], __float_as_int(rm1[r]));
    }
  }
  __syncthreads();

  for (int i=tid;i<512;i+=256){
    int bb=i>>5, c2=i&31;
    A16[bb*164 + 128 + c2] = (_Float16)__int_as_float(pooled[i]);
  }
  __syncthreads();

  {
    half8 bfF[2][5];
    #pragma unroll
    for (int nt2=0;nt2<2;++nt2)
      #pragma unroll
      for (int kc=0;kc<5;++kc)
        bfF[nt2][kc] = ld8(fus_wf + ((wv*2+nt2)*16+cb)*164 + kc*32 + q*8);
    const float fb0 = fus_b[(wv*2)*16+cb];
    const float fb1 = fus_b[(wv*2+1)*16+cb];
    floatx4 C0 = {0.f,0.f,0.f,0.f}, C1 = {0.f,0.f,0.f,0.f};
    #pragma unroll
    for (int kc=0;kc<5;++kc){
      half8 a = ld8(A16 + cb*164 + kc*32 + q*8);
      C0 = MFMA16(a, bfF[0][kc], C0);
      C1 = MFMA16(a, bfF[1][kc], C1);
    }
    #pragma unroll
    for (int r=0;r<4;++r){
      const long row = base + q*4 + r;
      fused[row*128 + (wv*2)*16+cb]   = tanh_raw(C0[r]+fb0);
      fused[row*128 + (wv*2+1)*16+cb] = tanh_raw(C1[r]+fb1);
    }
  }
}

// ---------------------------------------------------------------------------
// Decoder with FOLDED feedback: pure LSTM on whhp/biasp; 16 MFMA + ONE barrier
// per step; projection post-barrier straight to global (not on critical path).
// t=0 correction: seed MFMA with NEGATED w_ih against pred(-1)=ow·h0+ob.
// ---------------------------------------------------------------------------
__global__ __launch_bounds__(512, 4) void dec_mfma(
    const float* __restrict__ fused,
    const _Float16* __restrict__ whhp, const float* __restrict__ biasp,
    const float* __restrict__ w_ih,
    const float* __restrict__ out_w, const float* __restrict__ out_b,
    float* __restrict__ out)
{
  __shared__ _Float16 h_lds[2][16][136];
  __shared__ __align__(16) _Float16 wib[8][4][17][8]; // negated w_ih | zeros row
  __shared__ float ow_lds[2][128];
  __shared__ float pred_lds[16][2];

  const int tid  = threadIdx.x;
  const int wv   = tid >> 6;
  const int lane = tid & 63;
  const int q    = lane >> 4;
  const int cb   = lane & 15;
  const long base = (long)blockIdx.x * 16;

  for (int i=tid;i<256;i+=512) ow_lds[i>>7][i&127] = out_w[i];
  for (int i=tid;i<2048;i+=512) h_lds[0][i>>7][i&127] = (_Float16)fused[base*128 + i];
  for (int i=tid;i<2048;i+=512) h_lds[1][i>>7][i&127] = (_Float16)0.f;

  if (q == 0){
    #pragma unroll
    for (int g=0; g<4; ++g){
      const float sc = (g==2) ? L2E2 : L2E;
      const int col = g*128 + wv*16 + cb;
      _Float16* d = &wib[wv][g][cb][0];
      d[0] = (_Float16)(-w_ih[col*2+0]*sc);
      d[1] = (_Float16)(-w_ih[col*2+1]*sc);
      #pragma unroll
      for (int j=2;j<8;++j) d[j] = (_Float16)0.f;
    }
  } else if (lane == 16){
    #pragma unroll
    for (int g=0; g<4; ++g){
      _Float16* d = &wib[wv][g][16][0];
      #pragma unroll
      for (int j=0;j<8;++j) d[j] = (_Float16)0.f;
    }
  }

  half8 bfrag[4][4];
  float bias_r[4][4];
  #pragma unroll
  for (int g=0; g<4; ++g){
    const int col = g*128 + wv*16 + cb;
    #pragma unroll
    for (int r=0; r<4; ++r) bias_r[g][r] = biasp[g*128 + wv*16 + q*4 + r];
    #pragma unroll
    for (int kc=0; kc<4; ++kc)
      bfrag[g][kc] = ld8(whhp + (long)col*128 + kc*32 + q*8);
  }
  float ob0 = out_b[0], ob1 = out_b[1];
  __syncthreads();

  // pred(-1) = ow · h0 + ob  → pred_lds
  {
    int pair = tid>>3, part = tid&7;
    if (pair < 32){
      int m = pair>>1, oc = pair&1;
      const float* owp = ow_lds[oc];
      float v = 0.f;
      #pragma unroll
      for (int k=part*16; k<part*16+16; ++k) v += owp[k]*(float)h_lds[0][m][k];
      v += __shfl_down(v, 4, 8);
      v += __shfl_down(v, 2, 8);
      v += __shfl_down(v, 1, 8);
      if (part==0) pred_lds[m][oc] = v + (oc ? ob1 : ob0);
    }
  }
  __syncthreads();

  const _Float16* wibp = &wib[wv][0][(q==0)?cb:16][0];  // gate stride = 136 f16
  float c_reg[4] = {0,0,0,0};
  half4v hv;
  const floatx4 ZERO4 = {0.f,0.f,0.f,0.f};

  for (int t=0; t<25; ++t){
    const _Float16* hrow = &h_lds[t&1][cb][0];

    floatx4 acc[4];
    #pragma unroll
    for (int g=0; g<4; ++g)
      #pragma unroll
      for (int r=0; r<4; ++r) acc[g][r] = bias_r[g][r];

    if (t == 0){   // subtract spurious w_ih·pred(-1) injected by the fold
      half8 pb = {0,0,0,0,0,0,0,0};
      if (q == 0){
        pb[0] = (_Float16)pred_lds[cb][0];
        pb[1] = (_Float16)pred_lds[cb][1];
      }
      #pragma unroll
      for (int g=0; g<4; ++g){
        half8 w = *(const half8*)(wibp + g*136);
        acc[g] = MFMA16(w, pb, acc[g]);
      }
    }
    #pragma unroll
    for (int kc=0; kc<4; ++kc){
      half8 b = *(const half8*)(hrow + kc*32 + q*8);
      #pragma unroll
      for (int g=0; g<4; ++g)
        acc[g] = MFMA16(bfrag[g][kc], b, acc[g]);
    }
    #pragma unroll
    for (int r=0; r<4; ++r)
      hv[r] = (_Float16)lstm_cell(acc[0][r], acc[1][r], acc[2][r], acc[3][r], c_reg[r]);
    _Float16 (*hw)[136] = h_lds[(t+1)&1];
    *(half4v*)&hw[cb][wv*16 + q*4] = hv;
    __syncthreads();    // single barrier: orders h(t+1) for projection + next step
    {
      int pair = tid>>3, part = tid&7;
      if (pair < 32){
        int m = pair>>1, oc = pair&1;
        const float* owp = ow_lds[oc];
        float v = 0.f;
        #pragma unroll
        for (int k=part*16; k<part*16+16; ++k) v += owp[k]*(float)hw[m][k];
        v += __shfl_down(v, 4, 8);
        v += __shfl_down(v, 2, 8);
        v += __shfl_down(v, 1, 8);
        if (part==0)
          out[(base+m)*50 + t*2 + oc] = v + (oc ? ob1 : ob0);
      }
    }
    // no second barrier: next step's write targets the OTHER buffer, and its
    // ordering vs this step's reads is covered by the barrier above.
  }
}

// ---------------------------------------------------------------------------
extern "C" void kernel_launch(void* const* d_in, const int* in_sizes, int n_in,
                              void* d_out, int out_size, void* d_ws, size_t ws_size,
                              hipStream_t stream)
{
  (void)in_sizes; (void)n_in; (void)out_size; (void)ws_size;
  const float* target   = (const float*)d_in[0];
  const float* neigh    = (const float*)d_in[1];
  const float* enc_w_ih = (const float*)d_in[4];
  const float* enc_w_hh = (const float*)d_in[5];
  const float* enc_b_ih = (const float*)d_in[6];
  const float* enc_b_hh = (const float*)d_in[7];
  const float* nb_w_ih  = (const float*)d_in[8];
  const float* nb_w_hh  = (const float*)d_in[9];
  const float* nb_b_ih  = (const float*)d_in[10];
  const float* nb_b_hh  = (const float*)d_in[11];
  const float* w1       = (const float*)d_in[12];
  const float* b1       = (const float*)d_in[13];
  const float* w2       = (const float*)d_in[14];
  const float* b2       = (const float*)d_in[15];
  const float* fus_w    = (const float*)d_in[16];
  const float* fus_b    = (const float*)d_in[17];
  const float* dec_w_ih = (const float*)d_in[18];
  const float* dec_w_hh = (const float*)d_in[19];
  const float* dec_b_ih = (const float*)d_in[20];
  const float* dec_b_hh = (const float*)d_in[21];
  const float* out_w    = (const float*)d_in[22];
  const float* out_b    = (const float*)d_in[23];

  char* ws = (char*)d_ws;
  _Float16* h_nb16  = (_Float16*)ws;                       // 16 MB
  _Float16* h_enc16 = (_Float16*)(ws + (16u<<20));         // 2 MB
  float*    fusedp  = (float*)(ws + (18u<<20));            // 4 MB
  char* aux = ws + (22u<<20);
  _Float16* w1f    = (_Float16*)aux;                       // 152,064 B
  _Float16* w2f    = (_Float16*)(aux + 152064);            // 39,168 B
  _Float16* fus_wf = (_Float16*)(aux + 152064 + 39168);    // 41,984 B
  float*    v2bg   = (float*)(aux + 233216);               // 8,192 B
  float*    bgmaxp = (float*)(aux + 241408);               // 128 B
  _Float16* whhp   = (_Float16*)(aux + 241536);            // 131,072 B
  float*    biasp  = (float*)(aux + 241536 + 131072);      // 2,048 B

  prep_kernel<<<64, 256, 0, stream>>>(w1, b1, w2, b2, fus_w,
                                      dec_w_ih, dec_w_hh, dec_b_ih, dec_b_hh,
                                      out_w, out_b,
                                      w1f, w2f, fus_wf, whhp, biasp, v2bg, bgmaxp);
  lstm_all<<<4608, 512, 0, stream>>>(target, neigh,
                                     enc_w_ih, enc_w_hh, enc_b_ih, enc_b_hh,
                                     nb_w_ih, nb_w_hh, nb_b_ih, nb_b_hh,
                                     h_enc16, h_nb16);
  social_fuse<<<512, 256, 0, stream>>>(h_enc16, h_nb16, w1f, w2f, fus_wf,
                                       b1, v2bg, bgmaxp, fus_b, fusedp);
  dec_mfma<<<512, 512, 0, stream>>>(fusedp, whhp, biasp, dec_w_ih,
                                    out_w, out_b, (float*)d_out);
}

// Round 11
// 489.381 us; speedup vs baseline: 1.2336x; 1.0330x over previous
//
#include <hip/hip_runtime.h>

typedef _Float16 half8  __attribute__((ext_vector_type(8)));
typedef _Float16 half4v __attribute__((ext_vector_type(4)));
typedef float  floatx4  __attribute__((ext_vector_type(4)));

#define MFMA16(A,B,C) __builtin_amdgcn_mfma_f32_16x16x32_f16((A),(B),(C),0,0,0)

#define L2E  1.4426950408889634f
#define L2E2 2.8853900817779268f

__device__ __forceinline__ float rcpf(float x){ return __builtin_amdgcn_rcpf(x); }
__device__ __forceinline__ float ex2(float x){ return __builtin_amdgcn_exp2f(x); }
__device__ __forceinline__ float tanh_raw(float c){
  return 1.0f - 2.0f*rcpf(1.0f + ex2(L2E2*c));
}
__device__ __forceinline__ half8 ld8(const _Float16* p){
  half4v a = *(const half4v*)p;
  half4v b = *(const half4v*)(p+4);
  return __builtin_shufflevector(a,b,0,1,2,3,4,5,6,7);
}

// Fused LSTM cell (exact algebra, 8 trans): c'=c/(1+B)+(C-1)/((1+A)(1+C));
// h=(E-1)/((1+F)(1+E)) with A=2^-yi B=2^-yf C=2^yg F=2^-yo E=2^(2L c').
__device__ __forceinline__ float lstm_cell(float yi, float yf, float yg, float yo,
                                           float& c){
  float A = ex2(-yi), B = ex2(-yf), C = ex2(yg);
  float r1 = rcpf(1.0f + B);
  float r2 = rcpf((1.0f + A)*(1.0f + C));
  float cn = c*r1 + (C - 1.0f)*r2;
  c = cn;
  float F = ex2(-yo), E = ex2(L2E2*cn);
  float r3 = rcpf((1.0f + F)*(1.0f + E));
  return (E - 1.0f)*r3;
}

// grid geometry tables (compile-time foldable)
static __device__ constexpr int DY[27] = {0,0,0,0,0,0,0,0, 1,1,1,1,1,1,1,1, 2,2, 3,3,3,4,4,4,5,5,5};
static __device__ constexpr int DX[27] = {0,1,2,3,4,5,6,7, 0,1,2,3,4,5,6,7, 0,1, 3,4,5,3,4,5,3,4,5};
static __device__ constexpr int PY[9]  = {0,0,0,0,0,0,0,1,4};
static __device__ constexpr int PX[9]  = {1,2,3,4,5,6,7,0,4};
static __device__ constexpr int OY[46] = {0,0,0,0,0,0,0,0, 1,1,1,1,1,1,1,1, 2,2,2,2,2,2,2,2,
                                          3,3,3,3,3,3,3, 4,4,4,4,4, 5,5,5,5,5, 6,6,6,6,6};
static __device__ constexpr int OX[46] = {0,1,2,3,4,5,6,7, 0,1,2,3,4,5,6,7, 0,1,2,3,4,5,6,7,
                                          0,1,2,3,4,5,6, 2,3,4,5,6, 2,3,4,5,6, 2,3,4,5,6};
__device__ constexpr int d1idx(int iy,int ix){
  return (iy<0||iy>7||ix<0||ix>7) ? -1 :
         (iy<=1) ? iy*8+ix :
         (iy==2 && ix<=1) ? 16+ix :
         (iy>=3 && iy<=5 && ix>=3 && ix<=5) ? 18+(iy-3)*3+(ix-3) : -1;
}

// ---------------------------------------------------------------------------
// Combined encoder (unchanged from R8): transposed MFMA, merged-K, 1 barrier.
// ---------------------------------------------------------------------------
__global__ __launch_bounds__(512, 4) void lstm_all(
    const float* __restrict__ target, const float* __restrict__ neigh,
    const float* __restrict__ e_wih, const float* __restrict__ e_whh,
    const float* __restrict__ e_bih, const float* __restrict__ e_bhh,
    const float* __restrict__ n_wih, const float* __restrict__ n_whh,
    const float* __restrict__ n_bih, const float* __restrict__ n_bhh,
    _Float16* __restrict__ h_enc16, _Float16* __restrict__ h_nb16)
{
  __shared__ _Float16 h_lds[2][16][136];
  __shared__ _Float16 xf16[16][168];
  __shared__ __align__(16) _Float16 wihb[8][4][17][8];

  const int tid  = threadIdx.x;
  const int wv   = tid >> 6;
  const int lane = tid & 63;
  const int q    = lane >> 4;
  const int cb   = lane & 15;

  const bool enc = (blockIdx.x < 512);
  const float* x   = enc ? target : neigh;
  const float* wih = enc ? e_wih : n_wih;
  const float* whh = enc ? e_whh : n_whh;
  const float* bih = enc ? e_bih : n_bih;
  const float* bhh = enc ? e_bhh : n_bhh;
  _Float16* hout   = enc ? h_enc16 : h_nb16;
  const long base  = enc ? (long)blockIdx.x*16 : (long)(blockIdx.x-512)*16;

  for (int i = tid; i < 16*168; i += 512){
    int seq = i/168, rem = i%168, t = rem>>3, f = rem&7;
    float v = 0.f;
    if (t < 20) v = (f < 7) ? x[base*140 + seq*140 + t*7 + f] : 1.0f;
    xf16[seq][rem] = (_Float16)v;
  }
  for (int i = tid; i < 2*16*136; i += 512) ((_Float16*)h_lds)[i] = (_Float16)0.f;

  if (q == 0){
    #pragma unroll
    for (int g=0; g<4; ++g){
      const float sc = (g==2) ? L2E2 : L2E;
      const int col = g*128 + wv*16 + cb;
      _Float16* d = &wihb[wv][g][cb][0];
      #pragma unroll
      for (int j=0;j<7;++j) d[j] = (_Float16)(wih[col*7+j]*sc);
      d[7] = (_Float16)((bih[col]+bhh[col])*sc);
    }
  } else if (lane == 16){
    #pragma unroll
    for (int g=0; g<4; ++g){
      _Float16* d = &wihb[wv][g][16][0];
      #pragma unroll
      for (int j=0;j<8;++j) d[j] = (_Float16)0.f;
    }
  }

  half8 bfrag[4][4];
  #pragma unroll
  for (int g=0; g<4; ++g){
    const float sc = (g==2) ? L2E2 : L2E;
    const int col = g*128 + wv*16 + cb;
    #pragma unroll
    for (int kc=0; kc<4; ++kc){
      const float* src = whh + (long)col*128 + kc*32 + q*8;
      half8 f;
      #pragma unroll
      for (int j=0;j<8;++j) f[j] = (_Float16)(src[j]*sc);
      bfrag[g][kc] = f;
    }
  }
  __syncthreads();

  const _Float16* bxp = &wihb[wv][0][(q==0)?cb:16][0];
  const _Float16* a4p = (q==0) ? &xf16[cb][0] : &wihb[wv][0][16][0];
  const int a4step = (q==0) ? 8 : 0;
  half8 a4 = *(const half8*)a4p;
  a4p += a4step;

  float c_reg[4] = {0,0,0,0};
  half4v hv = {0,0,0,0};
  const floatx4 ZERO4 = {0.f,0.f,0.f,0.f};

  for (int t=0; t<20; ++t){
    const _Float16* hrow = &h_lds[t&1][cb][0];

    floatx4 acc[4];
    #pragma unroll
    for (int g=0; g<4; ++g){
      half8 bx = *(const half8*)(bxp + g*136);
      acc[g] = MFMA16(bx, a4, ZERO4);
    }
    #pragma unroll
    for (int kc=0; kc<4; ++kc){
      half8 b = *(const half8*)(hrow + kc*32 + q*8);
      #pragma unroll
      for (int g=0; g<4; ++g)
        acc[g] = MFMA16(bfrag[g][kc], b, acc[g]);
    }
    #pragma unroll
    for (int r=0; r<4; ++r)
      hv[r] = (_Float16)lstm_cell(acc[0][r], acc[1][r], acc[2][r], acc[3][r], c_reg[r]);
    *(half4v*)&h_lds[(t+1)&1][cb][wv*16 + q*4] = hv;
    a4 = *(const half8*)a4p;
    a4p += a4step;
    __syncthreads();
  }

  *(half4v*)&hout[(base + cb)*128 + wv*16 + q*4] = hv;
}

// ---------------------------------------------------------------------------
// Prep: conv/fusion weight layouts + conv2 background + decoder fold.
// ---------------------------------------------------------------------------
__global__ void prep_kernel(const float* __restrict__ w1, const float* __restrict__ b1,
                            const float* __restrict__ w2, const float* __restrict__ b2,
                            const float* __restrict__ fus_w,
                            const float* __restrict__ dec_wih, const float* __restrict__ dec_whh,
                            const float* __restrict__ dec_bih, const float* __restrict__ dec_bhh,
                            const float* __restrict__ out_w, const float* __restrict__ out_b,
                            _Float16* __restrict__ w1f, _Float16* __restrict__ w2f,
                            _Float16* __restrict__ fus_wf,
                            _Float16* __restrict__ whhp, float* __restrict__ biasp,
                            float* __restrict__ v2bg, float* __restrict__ bgmax)
{
  const int tid = threadIdx.x;
  const int gid = blockIdx.x*256 + tid;
  const int gstride = gridDim.x*256;
  for (int i = gid; i < 9*64*128; i += gstride){
    int s = i>>13, rem = i&8191, c1 = rem>>7, ci = rem&127;
    w1f[s*8448 + c1*132 + ci] = (_Float16)w1[c1*1152 + ci*9 + s];
  }
  for (int i = gid; i < 9*32*64; i += gstride){
    int s = i>>11, rem = i&2047, c2 = rem>>6, ci = rem&63;
    w2f[s*2176 + c2*68 + ci] = (_Float16)w2[c2*576 + ci*9 + s];
  }
  for (int i = gid; i < 128*160; i += gstride){
    int n = i/160, k = i%160;
    fus_wf[n*164 + k] = (_Float16)fus_w[i];
  }
  for (int i = gid; i < 512*128; i += gstride){
    int col = i>>7, k = i&127;
    float sc = ((col>>7)==2) ? L2E2 : L2E;
    float v = dec_whh[i] + dec_wih[col*2+0]*out_w[k] + dec_wih[col*2+1]*out_w[128+k];
    whhp[i] = (_Float16)(v*sc);
  }
  for (int i = gid; i < 512; i += gstride){
    float sc = ((i>>7)==2) ? L2E2 : L2E;
    biasp[i] = (dec_bih[i] + dec_bhh[i] + dec_wih[i*2+0]*out_b[0]
                + dec_wih[i*2+1]*out_b[1])*sc;
  }
  if (blockIdx.x == 0){
    __shared__ float S[288];
    __shared__ int bgm[32];
    for (int i=tid;i<288;i+=256){
      int c2=i/9, s=i%9;
      float a=0.f;
      for (int ci=0;ci<64;++ci) a += w2[c2*576+ci*9+s]*fmaxf(b1[ci],0.f);
      S[i]=a;
    }
    if (tid<32) bgm[tid]=0;
    __syncthreads();
    for (int i=tid;i<2048;i+=256){
      int cell=i>>5, c2=i&31, y=cell>>3, xx=cell&7;
      float a=b2[c2];
      for (int dy=0;dy<3;++dy){ int iy=y+dy-1; if((unsigned)iy>7u) continue;
        for (int dx=0;dx<3;++dx){ int ix=xx+dx-1; if((unsigned)ix>7u) continue;
          a += S[c2*9+dy*3+dx]; } }
      v2bg[cell*32+c2]=a;
      bool aff = (y<=2) || (y==3 && xx<=6) || (y>=4 && y<=6 && xx>=2 && xx<=6);
      if(!aff) atomicMax(&bgm[c2], __float_as_int(fmaxf(a,0.f)));
    }
    __syncthreads();
    if (tid<32) bgmax[tid]=__int_as_float(bgm[tid]);
  }
}

// ---------------------------------------------------------------------------
// Social pooling + sparse conv + maxpool + fusion — now 512 threads / 8 waves
// (same 104 KB LDS, same 16-batch tile). R1-R9 ran 4 waves = 1 wave/SIMD with
// 1 block/CU: zero latency hiding. 8 waves = 2/SIMD (VGPR 236×2=472<512).
// Work split: conv1 by (c1-slice = wv&3, cell parity = wv>>2); conv2 by
// oc&7==wv; fusion by n-tile = wv. d1 writes stay writer-disjoint.
// ---------------------------------------------------------------------------
__global__ __launch_bounds__(512, 1) void social_fuse(
    const _Float16* __restrict__ h_enc, const _Float16* __restrict__ h_nb,
    const _Float16* __restrict__ w1f, const _Float16* __restrict__ w2f,
    const _Float16* __restrict__ fus_wf,
    const float* __restrict__ b1, const float* __restrict__ v2bg,
    const float* __restrict__ bgmax, const float* __restrict__ fus_b,
    float* __restrict__ fused)
{
  __shared__ __align__(16) _Float16 vecs[9*16*132];
  __shared__ __align__(16) _Float16 d1[27*16*68];
  __shared__ __align__(16) _Float16 A16[16*164];
  __shared__ int pooled[512];

  const int tid  = threadIdx.x;
  const int wv   = tid >> 6;
  const int lane = tid & 63;
  const int q    = lane >> 4;
  const int cb   = lane & 15;
  const long base = (long)blockIdx.x * 16;

  for (int i=tid; i<9*16*32; i+=512){
    int p = i>>9, rem = i&511, bb = rem>>5, j = rem&31;
    const _Float16* src = (p<8) ? (h_nb + (((base+bb))*8 + p)*128 + j*4)
                                : (h_enc + (base+bb)*128 + j*4);
    *(unsigned long long*)(vecs + p*2112 + bb*132 + j*4) = *(const unsigned long long*)src;
  }
  for (int i=tid; i<512; i+=512){
    int bb=i>>5, j=i&31;
    *(unsigned long long*)(A16 + bb*164 + j*4) =
        *(const unsigned long long*)(h_enc + (base+bb)*128 + j*4);
  }
  for (int i=tid; i<512; i+=512) pooled[i] = __float_as_int(bgmax[i&31]);
  __syncthreads();

  // ---- conv1: wave = (c1-slice wv&3, cell-parity wv>>2) ----
  {
    const int c1lane = (wv&3)*16 + cb;
    const int half   = wv >> 2;
    half8 bf1[9][4];
    #pragma unroll
    for (int s=0;s<9;++s)
      #pragma unroll
      for (int kc=0;kc<4;++kc)
        bf1[s][kc] = ld8(w1f + s*8448 + c1lane*132 + kc*32 + q*8);
    const float b1v = b1[c1lane];
    const float bg  = fmaxf(b1v, 0.f);

    #pragma unroll
    for (int ci=0; ci<27; ++ci){
      if ((ci & 1) != half) continue;
      const int y = DY[ci], x = DX[ci];
      floatx4 C = {0.f,0.f,0.f,0.f};
      #pragma unroll
      for (int p=0;p<9;++p){
        const int dy = PY[p]-y+1, dx = PX[p]-x+1;
        if (dy>=0 && dy<3 && dx>=0 && dx<3){
          const int s = dy*3+dx;
          const _Float16* ap = vecs + p*2112 + cb*132 + q*8;
          #pragma unroll
          for (int kc=0;kc<4;++kc)
            C = MFMA16(ld8(ap + kc*32), bf1[s][kc], C);
        }
      }
      _Float16* dp = d1 + ci*1088 + c1lane;
      #pragma unroll
      for (int r=0;r<4;++r)
        dp[(q*4+r)*68] = (_Float16)(fmaxf(b1v + C[r], 0.f) - bg);
    }
  }
  __syncthreads();

  // ---- conv2 + maxpool: out-cells split 8 ways ----
  {
    half8 bf2[9][2][2];
    #pragma unroll
    for (int s=0;s<9;++s)
      #pragma unroll
      for (int nt=0;nt<2;++nt)
        #pragma unroll
        for (int kc=0;kc<2;++kc)
          bf2[s][nt][kc] = ld8(w2f + s*2176 + (nt*16+cb)*68 + kc*32 + q*8);

    float rm0[4] = {0,0,0,0}, rm1[4] = {0,0,0,0};
    #pragma unroll
    for (int oc=0; oc<46; ++oc){
      if ((oc & 7) != wv) continue;
      const int y = OY[oc], x = OX[oc];
      const int cell = y*8+x;
      float v0 = v2bg[cell*32 + cb];
      float v1 = v2bg[cell*32 + 16 + cb];
      floatx4 C0 = {v0,v0,v0,v0}, C1 = {v1,v1,v1,v1};
      #pragma unroll
      for (int dy=0;dy<3;++dy)
        #pragma unroll
        for (int dx=0;dx<3;++dx){
          const int dc = d1idx(y+dy-1, x+dx-1);
          if (dc < 0) continue;
          const int s = dy*3+dx;
          const _Float16* ap = d1 + dc*1088 + cb*68 + q*8;
          #pragma unroll
          for (int kc=0;kc<2;++kc){
            half8 a = ld8(ap + kc*32);
            C0 = MFMA16(a, bf2[s][0][kc], C0);
            C1 = MFMA16(a, bf2[s][1][kc], C1);
          }
        }
      #pragma unroll
      for (int r=0;r<4;++r){
        rm0[r] = fmaxf(rm0[r], fmaxf(C0[r],0.f));
        rm1[r] = fmaxf(rm1[r], fmaxf(C1[r],0.f));
      }
    }
    #pragma unroll
    for (int r=0;r<4;++r){
      atomicMax(&pooled[(q*4+r)*32 + cb],      __float_as_int(rm0[r]));
      atomicMax(&pooled[(q*4+r)*32 + 16 + cb], __float_as_int(rm1[r]));
    }
  }
  __syncthreads();

  for (int i=tid;i<512;i+=512){
    int bb=i>>5, c2=i&31;
    A16[bb*164 + 128 + c2] = (_Float16)__int_as_float(pooled[i]);
  }
  __syncthreads();

  // ---- fusion: wave wv owns n-tile wv (16 outputs) ----
  {
    half8 bfF[5];
    #pragma unroll
    for (int kc=0;kc<5;++kc)
      bfF[kc] = ld8(fus_wf + (wv*16+cb)*164 + kc*32 + q*8);
    const float fb = fus_b[wv*16+cb];
    floatx4 C0 = {0.f,0.f,0.f,0.f};
    #pragma unroll
    for (int kc=0;kc<5;++kc){
      half8 a = ld8(A16 + cb*164 + kc*32 + q*8);
      C0 = MFMA16(a, bfF[kc], C0);
    }
    #pragma unroll
    for (int r=0;r<4;++r){
      const long row = base + q*4 + r;
      fused[row*128 + wv*16+cb] = tanh_raw(C0[r]+fb);
    }
  }
}

// ---------------------------------------------------------------------------
// Decoder with folded feedback (unchanged from R9).
// ---------------------------------------------------------------------------
__global__ __launch_bounds__(512, 4) void dec_mfma(
    const float* __restrict__ fused,
    const _Float16* __restrict__ whhp, const float* __restrict__ biasp,
    const float* __restrict__ w_ih,
    const float* __restrict__ out_w, const float* __restrict__ out_b,
    float* __restrict__ out)
{
  __shared__ _Float16 h_lds[2][16][136];
  __shared__ __align__(16) _Float16 wib[8][4][17][8];
  __shared__ float ow_lds[2][128];
  __shared__ float pred_lds[16][2];

  const int tid  = threadIdx.x;
  const int wv   = tid >> 6;
  const int lane = tid & 63;
  const int q    = lane >> 4;
  const int cb   = lane & 15;
  const long base = (long)blockIdx.x * 16;

  for (int i=tid;i<256;i+=512) ow_lds[i>>7][i&127] = out_w[i];
  for (int i=tid;i<2048;i+=512) h_lds[0][i>>7][i&127] = (_Float16)fused[base*128 + i];
  for (int i=tid;i<2048;i+=512) h_lds[1][i>>7][i&127] = (_Float16)0.f;

  if (q == 0){
    #pragma unroll
    for (int g=0; g<4; ++g){
      const float sc = (g==2) ? L2E2 : L2E;
      const int col = g*128 + wv*16 + cb;
      _Float16* d = &wib[wv][g][cb][0];
      d[0] = (_Float16)(-w_ih[col*2+0]*sc);
      d[1] = (_Float16)(-w_ih[col*2+1]*sc);
      #pragma unroll
      for (int j=2;j<8;++j) d[j] = (_Float16)0.f;
    }
  } else if (lane == 16){
    #pragma unroll
    for (int g=0; g<4; ++g){
      _Float16* d = &wib[wv][g][16][0];
      #pragma unroll
      for (int j=0;j<8;++j) d[j] = (_Float16)0.f;
    }
  }

  half8 bfrag[4][4];
  float bias_r[4][4];
  #pragma unroll
  for (int g=0; g<4; ++g){
    const int col = g*128 + wv*16 + cb;
    #pragma unroll
    for (int r=0; r<4; ++r) bias_r[g][r] = biasp[g*128 + wv*16 + q*4 + r];
    #pragma unroll
    for (int kc=0; kc<4; ++kc)
      bfrag[g][kc] = ld8(whhp + (long)col*128 + kc*32 + q*8);
  }
  float ob0 = out_b[0], ob1 = out_b[1];
  __syncthreads();

  {
    int pair = tid>>3, part = tid&7;
    if (pair < 32){
      int m = pair>>1, oc = pair&1;
      const float* owp = ow_lds[oc];
      float v = 0.f;
      #pragma unroll
      for (int k=part*16; k<part*16+16; ++k) v += owp[k]*(float)h_lds[0][m][k];
      v += __shfl_down(v, 4, 8);
      v += __shfl_down(v, 2, 8);
      v += __shfl_down(v, 1, 8);
      if (part==0) pred_lds[m][oc] = v + (oc ? ob1 : ob0);
    }
  }
  __syncthreads();

  const _Float16* wibp = &wib[wv][0][(q==0)?cb:16][0];
  float c_reg[4] = {0,0,0,0};
  half4v hv;

  for (int t=0; t<25; ++t){
    const _Float16* hrow = &h_lds[t&1][cb][0];

    floatx4 acc[4];
    #pragma unroll
    for (int g=0; g<4; ++g)
      #pragma unroll
      for (int r=0; r<4; ++r) acc[g][r] = bias_r[g][r];

    if (t == 0){
      half8 pb = {0,0,0,0,0,0,0,0};
      if (q == 0){
        pb[0] = (_Float16)pred_lds[cb][0];
        pb[1] = (_Float16)pred_lds[cb][1];
      }
      #pragma unroll
      for (int g=0; g<4; ++g){
        half8 w = *(const half8*)(wibp + g*136);
        acc[g] = MFMA16(w, pb, acc[g]);
      }
    }
    #pragma unroll
    for (int kc=0; kc<4; ++kc){
      half8 b = *(const half8*)(hrow + kc*32 + q*8);
      #pragma unroll
      for (int g=0; g<4; ++g)
        acc[g] = MFMA16(bfrag[g][kc], b, acc[g]);
    }
    #pragma unroll
    for (int r=0; r<4; ++r)
      hv[r] = (_Float16)lstm_cell(acc[0][r], acc[1][r], acc[2][r], acc[3][r], c_reg[r]);
    _Float16 (*hw)[136] = h_lds[(t+1)&1];
    *(half4v*)&hw[cb][wv*16 + q*4] = hv;
    __syncthreads();
    {
      int pair = tid>>3, part = tid&7;
      if (pair < 32){
        int m = pair>>1, oc = pair&1;
        const float* owp = ow_lds[oc];
        float v = 0.f;
        #pragma unroll
        for (int k=part*16; k<part*16+16; ++k) v += owp[k]*(float)hw[m][k];
        v += __shfl_down(v, 4, 8);
        v += __shfl_down(v, 2, 8);
        v += __shfl_down(v, 1, 8);
        if (part==0)
          out[(base+m)*50 + t*2 + oc] = v + (oc ? ob1 : ob0);
      }
    }
  }
}

// ---------------------------------------------------------------------------
extern "C" void kernel_launch(void* const* d_in, const int* in_sizes, int n_in,
                              void* d_out, int out_size, void* d_ws, size_t ws_size,
                              hipStream_t stream)
{
  (void)in_sizes; (void)n_in; (void)out_size; (void)ws_size;
  const float* target   = (const float*)d_in[0];
  const float* neigh    = (const float*)d_in[1];
  const float* enc_w_ih = (const float*)d_in[4];
  const float* enc_w_hh = (const float*)d_in[5];
  const float* enc_b_ih = (const float*)d_in[6];
  const float* enc_b_hh = (const float*)d_in[7];
  const float* nb_w_ih  = (const float*)d_in[8];
  const float* nb_w_hh  = (const float*)d_in[9];
  const float* nb_b_ih  = (const float*)d_in[10];
  const float* nb_b_hh  = (const float*)d_in[11];
  const float* w1       = (const float*)d_in[12];
  const float* b1       = (const float*)d_in[13];
  const float* w2       = (const float*)d_in[14];
  const float* b2       = (const float*)d_in[15];
  const float* fus_w    = (const float*)d_in[16];
  const float* fus_b    = (const float*)d_in[17];
  const float* dec_w_ih = (const float*)d_in[18];
  const float* dec_w_hh = (const float*)d_in[19];
  const float* dec_b_ih = (const float*)d_in[20];
  const float* dec_b_hh = (const float*)d_in[21];
  const float* out_w    = (const float*)d_in[22];
  const float* out_b    = (const float*)d_in[23];

  char* ws = (char*)d_ws;
  _Float16* h_nb16  = (_Float16*)ws;                       // 16 MB
  _Float16* h_enc16 = (_Float16*)(ws + (16u<<20));         // 2 MB
  float*    fusedp  = (float*)(ws + (18u<<20));            // 4 MB
  char* aux = ws + (22u<<20);
  _Float16* w1f    = (_Float16*)aux;                       // 152,064 B
  _Float16* w2f    = (_Float16*)(aux + 152064);            // 39,168 B
  _Float16* fus_wf = (_Float16*)(aux + 152064 + 39168);    // 41,984 B
  float*    v2bg   = (float*)(aux + 233216);               // 8,192 B
  float*    bgmaxp = (float*)(aux + 241408);               // 128 B
  _Float16* whhp   = (_Float16*)(aux + 241536);            // 131,072 B
  float*    biasp  = (float*)(aux + 241536 + 131072);      // 2,048 B

  prep_kernel<<<64, 256, 0, stream>>>(w1, b1, w2, b2, fus_w,
                                      dec_w_ih, dec_w_hh, dec_b_ih, dec_b_hh,
                                      out_w, out_b,
                                      w1f, w2f, fus_wf, whhp, biasp, v2bg, bgmaxp);
  lstm_all<<<4608, 512, 0, stream>>>(target, neigh,
                                     enc_w_ih, enc_w_hh, enc_b_ih, enc_b_hh,
                                     nb_w_ih, nb_w_hh, nb_b_ih, nb_b_hh,
                                     h_enc16, h_nb16);
  social_fuse<<<512, 512, 0, stream>>>(h_enc16, h_nb16, w1f, w2f, fus_wf,
                                       b1, v2bg, bgmaxp, fus_b, fusedp);
  dec_mfma<<<512, 512, 0, stream>>>(fusedp, whhp, biasp, dec_w_ih,
                                    out_w, out_b, (float*)d_out);
}